// Round 11
// baseline (896.807 us; speedup 1.0000x reference)
//
#include <hip/hip_runtime.h>
#include <cmath>

// ---------------------------------------------------------------------------
// GCN_Message: graph VAE forward. Round 20 (= R19 + fused padded-slab CSR +
// s16 encoder means):
//   - CSR: count_rank(68us atomics) + scan(12us) + scatter(35us random
//     writes) replaced by ONE pass: place_pad does r=atomicAdd(&cnt[d],1);
//     esp[d*64+r]=src (atomic + scatter-write overlap in one pass; rowptr
//     becomes affine node*64; rank/scan/scatter deleted). Max degree ~40
//     (Poisson 16); r>=64 guard keeps any input in-bounds. Per-node edge
//     ORDER differs - proven harmless by R18 (passed, absmax identical).
//   - ggn2/ggn3 means stored s16 Q15 (means of Q15 values are in [-1,1]);
//     GEMM phase-1 MSRC=2 decodes in VGPRs. Err 1.5e-5 at layers 2-3.
//   - Decoder fp16 A-path (R19). GEMM: 512-thd BM=256 (R17), W-persistent
//     LDS (R16). Encoder acts s16 (R14). 3-term split-bf16 MFMA (R6).
// ---------------------------------------------------------------------------

constexpr int ACT_NONE = 0, ACT_TANH = 1, ACT_LEAKY = 2;
constexpr int PAD = 64;  // padded slab width (max degree ~40 for this graph)

typedef __attribute__((ext_vector_type(8))) __bf16 bf16x8;
typedef __attribute__((ext_vector_type(4))) float f32x4;
typedef __attribute__((ext_vector_type(4))) unsigned short u16x4;
typedef __attribute__((ext_vector_type(8))) unsigned short u16x8;

__device__ __forceinline__ unsigned short f2h(float x) {
  _Float16 h = (_Float16)x;
  unsigned short u;
  __builtin_memcpy(&u, &h, 2);
  return u;
}
__device__ __forceinline__ float h2f(unsigned short s) {
  _Float16 h;
  __builtin_memcpy(&h, &s, 2);
  return (float)h;
}
__device__ __forceinline__ float hlo(unsigned int u) {
  return h2f((unsigned short)(u & 0xffffu));
}
__device__ __forceinline__ float hhi(unsigned int u) {
  return h2f((unsigned short)(u >> 16));
}
__device__ __forceinline__ void split_bf16(float x, __bf16& h, __bf16& l) {
  h = (__bf16)x;
  l = (__bf16)(x - (float)h);
}
__device__ __forceinline__ unsigned short b2u(__bf16 b) {
  unsigned short u;
  __builtin_memcpy(&u, &b, 2);
  return u;
}

// elementwise split: fp32 -> bf16 hi/lo (total % 4 == 0)
__global__ __launch_bounds__(256) void split_x_kernel(const float* __restrict__ in,
                                                      __bf16* __restrict__ hi,
                                                      __bf16* __restrict__ lo, int total) {
  int i = (blockIdx.x * 256 + threadIdx.x) * 4;
  if (i >= total) return;
  float4 v = *(const float4*)(in + i);
  float vv[4] = {v.x, v.y, v.z, v.w};
  u16x4 h, l;
#pragma unroll
  for (int j = 0; j < 4; ++j) {
    __bf16 hb, lb;
    split_bf16(vv[j], hb, lb);
    h[j] = b2u(hb);
    l[j] = b2u(lb);
  }
  *(u16x4*)(hi + i) = h;
  *(u16x4*)(lo + i) = l;
}

// one-shot split of all 12 GEMM weight matrices into Whi/Wlo at fixed offsets
__global__ __launch_bounds__(256) void split_w_kernel(
    const float* p0, const float* p1, const float* p2, const float* p3,
    const float* p4, const float* p5, const float* p6, const float* p7,
    const float* p8, const float* p9, const float* p10, const float* p11,
    __bf16* __restrict__ hi, __bf16* __restrict__ lo) {
  int b = blockIdx.x;
  const float* src;
  int boff, doff;
  if      (b < 8)   { src = p0;  boff = b;       doff = 0; }
  else if (b < 16)  { src = p1;  boff = b - 8;   doff = 8192; }
  else if (b < 32)  { src = p2;  boff = b - 16;  doff = 16384; }
  else if (b < 48)  { src = p3;  boff = b - 32;  doff = 32768; }
  else if (b < 64)  { src = p4;  boff = b - 48;  doff = 49152; }
  else if (b < 80)  { src = p5;  boff = b - 64;  doff = 65536; }
  else if (b < 88)  { src = p6;  boff = b - 80;  doff = 81920; }
  else if (b < 96)  { src = p7;  boff = b - 88;  doff = 90112; }
  else if (b < 112) { src = p8;  boff = b - 96;  doff = 98304; }
  else if (b < 128) { src = p9;  boff = b - 112; doff = 114688; }
  else if (b < 136) { src = p10; boff = b - 128; doff = 131072; }
  else              { src = p11; boff = b - 136; doff = 139264; }
  int i = boff * 1024 + threadIdx.x * 4;
  float4 v = *(const float4*)(src + i);
  float vv[4] = {v.x, v.y, v.z, v.w};
  u16x4 h, l;
#pragma unroll
  for (int j = 0; j < 4; ++j) {
    __bf16 hb, lb;
    split_bf16(vv[j], hb, lb);
    h[j] = b2u(hb);
    l[j] = b2u(lb);
  }
  *(u16x4*)(hi + doff + i) = h;
  *(u16x4*)(lo + doff + i) = l;
}

// fused CSR: one atomic pass places edges into the padded slab esp[d*PAD+r]
__global__ __launch_bounds__(256) void place_pad_kernel(const int* __restrict__ src,
                                                        const int* __restrict__ dst,
                                                        int* __restrict__ cnt,
                                                        int* __restrict__ esp, int E) {
  int e = blockIdx.x * 256 + threadIdx.x;
  if (e < E) {
    int d = dst[e];
    int r = atomicAdd(&cnt[d], 1);
    if (r < PAD) esp[(size_t)d * PAD + r] = src[e];
    else atomicSub(&cnt[d], 1);  // unreachable for this graph; keeps bounds
  }
}

// inv[i] = 1/max(cnt[i],1)
__global__ __launch_bounds__(256) void inv_kernel(const int* __restrict__ cnt,
                                                  float* __restrict__ inv, int n) {
  int i = blockIdx.x * 256 + threadIdx.x;
  if (i < n) {
    int c = cnt[i];
    inv[i] = 1.0f / (float)(c > 1 ? c : 1);
  }
}

// fp32 gather (ggn1, D=64 from x): wave per node; writes split bf16 mean
__global__ __launch_bounds__(256) void gather_f32s_kernel(
    const float* __restrict__ in, const int* __restrict__ esp,
    const int* __restrict__ cnt, const float* __restrict__ inv,
    __bf16* __restrict__ Mhi, __bf16* __restrict__ Mlo, int n) {
  const int node = blockIdx.x * 4 + (threadIdx.x >> 6);
  const int lane = threadIdx.x & 63;
  if (node >= n) return;
  const int m = cnt[node];
  const float iv = inv[node];
  int myi = (lane < m) ? esp[(size_t)node * PAD + lane] : 0;
  float a0 = 0.f, a1 = 0.f, a2 = 0.f, a3 = 0.f;
  int s = 0;
  for (; s + 4 <= m; s += 4) {
    int i0 = __shfl(myi, s);
    int i1 = __shfl(myi, s + 1);
    int i2 = __shfl(myi, s + 2);
    int i3 = __shfl(myi, s + 3);
    a0 += in[(size_t)i0 * 64 + lane];
    a1 += in[(size_t)i1 * 64 + lane];
    a2 += in[(size_t)i2 * 64 + lane];
    a3 += in[(size_t)i3 * 64 + lane];
  }
  for (; s < m; ++s) {
    int i0 = __shfl(myi, s);
    a0 += in[(size_t)i0 * 64 + lane];
  }
  float mv = ((a0 + a1) + (a2 + a3)) * iv;
  __bf16 h, l;
  split_bf16(mv, h, l);
  Mhi[(size_t)node * 64 + lane] = h;
  Mlo[(size_t)node * 64 + lane] = l;
}

// int16 Q1.15 gather (encoder ggn2/ggn3): EXACT int32 neighbor sum;
// mean emitted as s16 Q15 (means of Q15 values are in [-1,1]).
__global__ __launch_bounds__(256) void gather_s16_kernel(
    const unsigned short* __restrict__ inq, const int* __restrict__ esp,
    const int* __restrict__ cnt, const float* __restrict__ inv,
    unsigned short* __restrict__ Ms, int n) {
  const int node = blockIdx.x * 4 + (threadIdx.x >> 6);
  const int lane = threadIdx.x & 63;
  if (node >= n) return;
  const int m = cnt[node];
  const float iv = inv[node];
  const unsigned int* bu = (const unsigned int*)inq;
  int myi = (lane < m) ? esp[(size_t)node * PAD + lane] : 0;
  int a0l = 0, a0h = 0, a1l = 0, a1h = 0;
  int a2l = 0, a2h = 0, a3l = 0, a3h = 0;
  int s = 0;
  for (; s + 4 <= m; s += 4) {
    int i0 = __shfl(myi, s);
    int i1 = __shfl(myi, s + 1);
    int i2 = __shfl(myi, s + 2);
    int i3 = __shfl(myi, s + 3);
    unsigned int u0 = bu[(size_t)i0 * 64 + lane];
    unsigned int u1 = bu[(size_t)i1 * 64 + lane];
    unsigned int u2 = bu[(size_t)i2 * 64 + lane];
    unsigned int u3 = bu[(size_t)i3 * 64 + lane];
    a0l += (int)(short)u0; a0h += ((int)u0) >> 16;
    a1l += (int)(short)u1; a1h += ((int)u1) >> 16;
    a2l += (int)(short)u2; a2h += ((int)u2) >> 16;
    a3l += (int)(short)u3; a3h += ((int)u3) >> 16;
  }
  for (; s < m; ++s) {
    int i0 = __shfl(myi, s);
    unsigned int u0 = bu[(size_t)i0 * 64 + lane];
    a0l += (int)(short)u0; a0h += ((int)u0) >> 16;
  }
  float sx = (float)((a0l + a1l) + (a2l + a3l)) * iv;
  float sy = (float)((a0h + a1h) + (a2h + a3h)) * iv;
  short qx = (short)__builtin_rintf(sx);
  short qy = (short)__builtin_rintf(sy);
  ((unsigned int*)Ms)[(size_t)node * 64 + lane] =
      (unsigned int)(unsigned short)qx | ((unsigned int)(unsigned short)qy << 16);
}

// fp16 gather, D=128 (dec2): wave per node; writes split bf16 mean
__global__ __launch_bounds__(256) void gather_h128_kernel(
    const unsigned short* __restrict__ inh, const int* __restrict__ esp,
    const int* __restrict__ cnt, const float* __restrict__ inv,
    __bf16* __restrict__ Mhi, __bf16* __restrict__ Mlo, int n) {
  const int node = blockIdx.x * 4 + (threadIdx.x >> 6);
  const int lane = threadIdx.x & 63;
  if (node >= n) return;
  const int m = cnt[node];
  const float iv = inv[node];
  const unsigned int* bu = (const unsigned int*)inh;
  int myi = (lane < m) ? esp[(size_t)node * PAD + lane] : 0;
  float a0x = 0.f, a0y = 0.f, a1x = 0.f, a1y = 0.f;
  float a2x = 0.f, a2y = 0.f, a3x = 0.f, a3y = 0.f;
  int s = 0;
  for (; s + 4 <= m; s += 4) {
    int i0 = __shfl(myi, s);
    int i1 = __shfl(myi, s + 1);
    int i2 = __shfl(myi, s + 2);
    int i3 = __shfl(myi, s + 3);
    unsigned int u0 = bu[(size_t)i0 * 64 + lane];
    unsigned int u1 = bu[(size_t)i1 * 64 + lane];
    unsigned int u2 = bu[(size_t)i2 * 64 + lane];
    unsigned int u3 = bu[(size_t)i3 * 64 + lane];
    a0x += hlo(u0); a0y += hhi(u0);
    a1x += hlo(u1); a1y += hhi(u1);
    a2x += hlo(u2); a2y += hhi(u2);
    a3x += hlo(u3); a3y += hhi(u3);
  }
  for (; s < m; ++s) {
    int i0 = __shfl(myi, s);
    unsigned int u0 = bu[(size_t)i0 * 64 + lane];
    a0x += hlo(u0); a0y += hhi(u0);
  }
  float rx = ((a0x + a1x) + (a2x + a3x)) * iv;
  float ry = ((a0y + a1y) + (a2y + a3y)) * iv;
  __bf16 h0, l0, h1, l1;
  split_bf16(rx, h0, l0);
  split_bf16(ry, h1, l1);
  ((unsigned int*)Mhi)[(size_t)node * 64 + lane] =
      (unsigned int)b2u(h0) | ((unsigned int)b2u(h1) << 16);
  ((unsigned int*)Mlo)[(size_t)node * 64 + lane] =
      (unsigned int)b2u(l0) | ((unsigned int)b2u(l1) << 16);
}

// fp16 gather, D=64 (dec3): half-wave per neighbor-pair member; fp32 out
__global__ __launch_bounds__(256) void gather_h64_kernel(
    const unsigned short* __restrict__ inh, const int* __restrict__ esp,
    const int* __restrict__ cnt, const float* __restrict__ inv,
    float* __restrict__ meanb, int n) {
  const int node = blockIdx.x * 4 + (threadIdx.x >> 6);
  const int lane = threadIdx.x & 63;
  if (node >= n) return;
  const int m = cnt[node];
  const float iv = inv[node];
  const unsigned int* bu = (const unsigned int*)inh;
  const int half = lane >> 5;
  const int hl = lane & 31;
  int myi = (lane < m) ? esp[(size_t)node * PAD + lane] : 0;
  float ax = 0.f, ay = 0.f, bx = 0.f, by = 0.f;
  int s = 0;
  for (; s + 4 <= m; s += 4) {
    int i0 = __shfl(myi, s + half);
    int i1 = __shfl(myi, s + 2 + half);
    unsigned int u0 = bu[(size_t)i0 * 32 + hl];
    unsigned int u1 = bu[(size_t)i1 * 32 + hl];
    ax += hlo(u0); ay += hhi(u0);
    bx += hlo(u1); by += hhi(u1);
  }
  for (; s < m; s += 2) {
    int t = s + half;
    if (t < m) {
      int i0 = __shfl(myi, t);
      unsigned int u0 = bu[(size_t)i0 * 32 + hl];
      ax += hlo(u0); ay += hhi(u0);
    }
  }
  float sx = ax + bx, sy = ay + by;
  sx += __shfl_xor(sx, 32);
  sy += __shfl_xor(sy, 32);
  if (half == 0)
    ((float2*)meanb)[(size_t)node * 32 + hl] = make_float2(sx * iv, sy * iv);
}

// thread per node: mean over 4-wide (padded float4) rows
__global__ __launch_bounds__(256) void gather_mean4_kernel(
    const float* __restrict__ y4, const int* __restrict__ esp,
    const int* __restrict__ cnt, const float* __restrict__ inv,
    float* __restrict__ mean4, int n) {
  int i = blockIdx.x * 256 + threadIdx.x;
  if (i >= n) return;
  const int m = cnt[i];
  const float iv = inv[i];
  float sx = 0.f, sy = 0.f, sz = 0.f;
  const float4* b = (const float4*)y4;
  for (int j = 0; j < m; ++j) {
    float4 v = b[esp[(size_t)i * PAD + j]];
    sx += v.x; sy += v.y; sz += v.z;
  }
  ((float4*)mean4)[i] = make_float4(sx * iv, sy * iv, sz * iv, 0.f);
}

// out[row,col] = act( (AGG ? mean@Wl^T : 0) + (ADDMEAN ? meanF : 0)
//                     + in@Wr^T + (BIAS ? b : 0) )
// 512-thread blocks (8 waves), BM=256; W panel persists in LDS per phase
// (row stride DI+8); A streamed global->VGPR, k-loop fully unrolled.
// ASRC/MSRC: 0 = bf16 hi/lo pair; 1 = fp16 single; 2 = s16 Q1.15 (1/2
// converted+split in VGPRs). ASRC applies to phase 0 (A), MSRC to phase 1
// (mean; pointer Mhi reinterpreted when MSRC != 0).
template <int DI, int DO, int ACT, bool AGG, bool ADDMEAN, bool BIAS, int SH,
          bool OSPLIT, int ASRC, int MSRC>
__global__ __launch_bounds__(512) void node_mfma_kernel(
    const __bf16* __restrict__ Ahi, const __bf16* __restrict__ Alo,
    const __bf16* __restrict__ Mhi, const __bf16* __restrict__ Mlo,
    const __bf16* __restrict__ Wrhi, const __bf16* __restrict__ Wrlo,
    const __bf16* __restrict__ Wlhi, const __bf16* __restrict__ Wllo,
    const float* __restrict__ bias, const float* __restrict__ meanF,
    float* __restrict__ out, float* __restrict__ out2,
    unsigned short* __restrict__ outh,
    __bf16* __restrict__ ohi, __bf16* __restrict__ olo, int n) {
  constexpr int BM = 256;
  constexpr int KSW = DI + 8;
  constexpr int CT = DO / 16;
  constexpr int EL = DO * DI / 512;
  __shared__ __align__(16) __bf16 Ws_hi[DO * KSW];
  __shared__ __align__(16) __bf16 Ws_lo[DO * KSW];

  const int wv = threadIdx.x >> 6;
  const int lane = threadIdx.x & 63;
  const int lm = lane & 15;
  const int lq = lane >> 4;
  const int row0 = blockIdx.x * BM;

  f32x4 acc[2][CT];
#pragma unroll
  for (int rt = 0; rt < 2; ++rt)
#pragma unroll
    for (int ct = 0; ct < CT; ++ct) acc[rt][ct] = (f32x4){0.f, 0.f, 0.f, 0.f};

  bf16x8 zf;
#pragma unroll
  for (int j = 0; j < 8; ++j) zf[j] = (__bf16)0.f;

  const int rA0 = row0 + wv * 32 + lm;
  const int rA1 = rA0 + 16;
  const bool ok0 = rA0 < n;
  const bool ok1 = rA1 < n;
  const int kofs = lq * 8;

  const int sc = (threadIdx.x * EL) / DI;
  const int sk = (threadIdx.x * EL) % DI;

  const int nphase = AGG ? 2 : 1;
#pragma unroll
  for (int phase = 0; phase < nphase; ++phase) {
    const __bf16* WH = (phase == 0) ? Wrhi : Wlhi;
    const __bf16* WL = (phase == 0) ? Wrlo : Wllo;
    if (phase > 0) __syncthreads();
#pragma unroll
    for (int j = 0; j < EL / 8; ++j) {
      *(bf16x8*)(&Ws_hi[sc * KSW + sk + j * 8]) =
          *(const bf16x8*)(WH + (size_t)sc * DI + sk + j * 8);
      *(bf16x8*)(&Ws_lo[sc * KSW + sk + j * 8]) =
          *(const bf16x8*)(WL + (size_t)sc * DI + sk + j * 8);
    }
    __syncthreads();

    const __bf16* AH = (phase == 0) ? Ahi : Mhi;
    const __bf16* AL = (phase == 0) ? Alo : Mlo;
    const int code = (phase == 0) ? ASRC : MSRC;
#pragma unroll
    for (int k0 = 0; k0 < DI; k0 += 32) {
      bf16x8 ah[2], al[2];
      if (code != 0) {
        // u16-coded A (fp16 or s16 Q1.15): load 8 shorts/row, convert+split
        const unsigned short* Q = (const unsigned short*)AH;
        u16x8 q0, q1;
        if (ok0) q0 = *(const u16x8*)(Q + (size_t)rA0 * DI + k0 + kofs);
        else {
#pragma unroll
          for (int j = 0; j < 8; ++j) q0[j] = 0;
        }
        if (ok1) q1 = *(const u16x8*)(Q + (size_t)rA1 * DI + k0 + kofs);
        else {
#pragma unroll
          for (int j = 0; j < 8; ++j) q1[j] = 0;
        }
#pragma unroll
        for (int j = 0; j < 8; ++j) {
          float v0, v1;
          if (code == 1) {
            v0 = h2f(q0[j]);
            v1 = h2f(q1[j]);
          } else {
            v0 = (float)(short)q0[j] * (1.0f / 32767.0f);
            v1 = (float)(short)q1[j] * (1.0f / 32767.0f);
          }
          __bf16 hb, lb;
          split_bf16(v0, hb, lb);
          ah[0][j] = hb; al[0][j] = lb;
          split_bf16(v1, hb, lb);
          ah[1][j] = hb; al[1][j] = lb;
        }
      } else {
        ah[0] = ok0 ? *(const bf16x8*)(AH + (size_t)rA0 * DI + k0 + kofs) : zf;
        al[0] = ok0 ? *(const bf16x8*)(AL + (size_t)rA0 * DI + k0 + kofs) : zf;
        ah[1] = ok1 ? *(const bf16x8*)(AH + (size_t)rA1 * DI + k0 + kofs) : zf;
        al[1] = ok1 ? *(const bf16x8*)(AL + (size_t)rA1 * DI + k0 + kofs) : zf;
      }
#pragma unroll
      for (int ct = 0; ct < CT; ++ct) {
        const int c = ct * 16 + lm;
        bf16x8 bh = *(const bf16x8*)(&Ws_hi[c * KSW + k0 + kofs]);
        bf16x8 bl = *(const bf16x8*)(&Ws_lo[c * KSW + k0 + kofs]);
#pragma unroll
        for (int rt = 0; rt < 2; ++rt) {
          acc[rt][ct] = __builtin_amdgcn_mfma_f32_16x16x32_bf16(ah[rt], bh, acc[rt][ct], 0, 0, 0);
          acc[rt][ct] = __builtin_amdgcn_mfma_f32_16x16x32_bf16(al[rt], bh, acc[rt][ct], 0, 0, 0);
          acc[rt][ct] = __builtin_amdgcn_mfma_f32_16x16x32_bf16(ah[rt], bl, acc[rt][ct], 0, 0, 0);
        }
      }
    }
  }

#pragma unroll
  for (int rt = 0; rt < 2; ++rt)
#pragma unroll
    for (int ct = 0; ct < CT; ++ct) {
      const int col = ct * 16 + lm;
      const float bval = BIAS ? bias[col] : 0.f;
      f32x4 a = acc[rt][ct];
#pragma unroll
      for (int r = 0; r < 4; ++r) {
        const int row = row0 + wv * 32 + rt * 16 + lq * 4 + r;
        if (row < n) {
          float t = a[r] + bval;
          if (ADDMEAN) t += meanF[(size_t)row * DO + col];
          if (ACT == ACT_TANH) t = tanhf(t);
          else if (ACT == ACT_LEAKY) t = (t > 0.f) ? t : 0.01f * t;
          if (out) out[(size_t)row * DO + col] = t;
          if (out2) out2[(size_t)row * DO + col] = t;
          if constexpr (SH == 1) {
            if (outh) outh[(size_t)row * DO + col] = f2h(t);
          } else if constexpr (SH == 2) {
            if (outh)
              outh[(size_t)row * DO + col] =
                  (unsigned short)(short)__builtin_rintf(t * 32767.0f);
          }
          if constexpr (OSPLIT) {
            __bf16 hb, lb;
            split_bf16(t, hb, lb);
            ohi[(size_t)row * DO + col] = hb;
            olo[(size_t)row * DO + col] = lb;
          }
        }
      }
    }
}

// y4[node] = hB[node] @ Wl^T (3 outputs, padded float4); wave per node
__global__ __launch_bounds__(256) void dec4_pre_kernel(
    const float* __restrict__ hB, const float* __restrict__ Wl,
    float* __restrict__ y4, int n) {
  const int node = blockIdx.x * 4 + (threadIdx.x >> 6);
  const int lane = threadIdx.x & 63;
  if (node >= n) return;
  float v = hB[(size_t)node * 64 + lane];
  float p0 = v * Wl[lane];
  float p1 = v * Wl[64 + lane];
  float p2 = v * Wl[128 + lane];
#pragma unroll
  for (int off = 32; off >= 1; off >>= 1) {
    p0 += __shfl_xor(p0, off);
    p1 += __shfl_xor(p1, off);
    p2 += __shfl_xor(p2, off);
  }
  if (lane == 0) ((float4*)y4)[node] = make_float4(p0, p1, p2, 0.f);
}

// out = mean4 + b + hB@Wr^T, scattered layout (z2[:,:2], z2[:,2]); wave/node
__global__ __launch_bounds__(256) void dec4_final_kernel(
    const float* __restrict__ hB, const float* __restrict__ mean4,
    const float* __restrict__ Wr, const float* __restrict__ bias,
    float* __restrict__ out, int n) {
  const int node = blockIdx.x * 4 + (threadIdx.x >> 6);
  const int lane = threadIdx.x & 63;
  if (node >= n) return;
  float v = hB[(size_t)node * 64 + lane];
  float p0 = v * Wr[lane];
  float p1 = v * Wr[64 + lane];
  float p2 = v * Wr[128 + lane];
#pragma unroll
  for (int off = 32; off >= 1; off >>= 1) {
    p0 += __shfl_xor(p0, off);
    p1 += __shfl_xor(p1, off);
    p2 += __shfl_xor(p2, off);
  }
  if (lane == 0) {
    float4 m = ((const float4*)mean4)[node];
    out[2 * (size_t)node]     = p0 + m.x + bias[0];
    out[2 * (size_t)node + 1] = p1 + m.y + bias[1];
    out[2 * (size_t)n + node] = p2 + m.z + bias[2];
  }
}

extern "C" void kernel_launch(void* const* d_in, const int* in_sizes, int n_in,
                              void* d_out, int out_size, void* d_ws, size_t ws_size,
                              hipStream_t stream) {
  const float* x = (const float*)d_in[0];
  const int* ei = (const int*)d_in[1];
  const int N = in_sizes[0] / 64;
  const int E = in_sizes[1] / 2;
  const int* src = ei;
  const int* dst = ei + E;
  const float* g1Wl = (const float*)d_in[2];
  const float* g1b  = (const float*)d_in[3];
  const float* g1Wr = (const float*)d_in[4];
  const float* g2Wl = (const float*)d_in[5];
  const float* g2b  = (const float*)d_in[6];
  const float* g2Wr = (const float*)d_in[7];
  const float* g3Wl = (const float*)d_in[8];
  const float* g3b  = (const float*)d_in[9];
  const float* g3Wr = (const float*)d_in[10];
  const float* t2W  = (const float*)d_in[11];
  const float* t2b  = (const float*)d_in[12];
  const float* d1W  = (const float*)d_in[13];
  const float* d1b  = (const float*)d_in[14];
  const float* d2Wl = (const float*)d_in[15];
  const float* d2b  = (const float*)d_in[16];
  const float* d2Wr = (const float*)d_in[17];
  const float* d3Wl = (const float*)d_in[18];
  const float* d3b  = (const float*)d_in[19];
  const float* d3Wr = (const float*)d_in[20];
  const float* d4Wl = (const float*)d_in[21];
  const float* d4b  = (const float*)d_in[22];
  const float* d4Wr = (const float*)d_in[23];

  const size_t N64 = (size_t)N * 64;
  const size_t N128 = (size_t)N * 128;

  char* w = (char*)d_ws;
  auto alloc = [&](size_t bytes) {
    char* p = w;
    w += (bytes + 255) & ~(size_t)255;
    return p;
  };
  __bf16* Ahi = (__bf16*)alloc(N128 * 2);   // enc act1 s16; dec2-out shA fp16
  __bf16* Alo = (__bf16*)alloc(N128 * 2);   // enc act2 s16
  float*  meanF = (float*)alloc(N128 * 4);  // aliased below
  __bf16* xhi = (__bf16*)alloc(N64 * 2);    // also muhi, also shC
  __bf16* xlo = (__bf16*)alloc(N64 * 2);    // also mulo
  __bf16* Whi = (__bf16*)alloc(147456 * 2);
  __bf16* Wlo = (__bf16*)alloc(147456 * 2);
  int*    cnt = (int*)alloc((size_t)N * 4);
  float*  inv = (float*)alloc((size_t)N * 4);
  int*    esp = (int*)alloc((size_t)N * PAD * 4);  // padded neighbor slab
  unsigned short* shB = (unsigned short*)alloc(N128 * 2);  // dec1 out fp16

  // encoder s16 activation buffers (alias Ahi/Alo; dead before decoder use)
  unsigned short* act1 = (unsigned short*)Ahi;  // ggn1 out; ggn2 in; ggn3 out; tr2 A
  unsigned short* act2 = (unsigned short*)Alo;  // ggn2 out; ggn3 in
  unsigned short* shA = (unsigned short*)Ahi;   // dec2 out fp16 (act1 dead after tr2)

  // aliases of meanF (disjoint lifetimes):
  __bf16* Mhi = (__bf16*)meanF;        // pair mean (ggn1, dec2)
  __bf16* Mlo = Mhi + N128;
  unsigned short* Ms16 = (unsigned short*)meanF;  // s16 mean (ggn2/ggn3)
  float*  y4 = meanF;                  // N x 4 (dec4)
  float*  mean4 = meanF + 4 * (size_t)N;
  float*  hBf = meanF + N64;           // N x 64 f32 (dec3 out -> dec4)
  // aliases of xhi/xlo:
  __bf16* muhi = xhi;
  __bf16* mulo = xlo;
  unsigned short* shC = (unsigned short*)xhi;

  float* out = (float*)d_out;
  float* mu  = out + 3 * (size_t)N;  // N x 64
  float* lv  = mu + 64 * (size_t)N;  // N x 64 (logvar == mu)

  const int NB = (N + 255) / 256;  // 512-thread GEMM blocks, BM=256
  const int GB = (N + 3) / 4;

  // weight split offsets (bf16 elems) in Whi/Wlo
  const __bf16 *W_g1Wl_h = Whi + 0,      *W_g1Wl_l = Wlo + 0;
  const __bf16 *W_g1Wr_h = Whi + 8192,   *W_g1Wr_l = Wlo + 8192;
  const __bf16 *W_g2Wl_h = Whi + 16384,  *W_g2Wl_l = Wlo + 16384;
  const __bf16 *W_g2Wr_h = Whi + 32768,  *W_g2Wr_l = Wlo + 32768;
  const __bf16 *W_g3Wl_h = Whi + 49152,  *W_g3Wl_l = Wlo + 49152;
  const __bf16 *W_g3Wr_h = Whi + 65536,  *W_g3Wr_l = Wlo + 65536;
  const __bf16 *W_t2W_h  = Whi + 81920,  *W_t2W_l  = Wlo + 81920;
  const __bf16 *W_d1W_h  = Whi + 90112,  *W_d1W_l  = Wlo + 90112;
  const __bf16 *W_d2Wl_h = Whi + 98304,  *W_d2Wl_l = Wlo + 98304;
  const __bf16 *W_d2Wr_h = Whi + 114688, *W_d2Wr_l = Wlo + 114688;
  const __bf16 *W_d3Wl_h = Whi + 131072, *W_d3Wl_l = Wlo + 131072;
  const __bf16 *W_d3Wr_h = Whi + 139264, *W_d3Wr_l = Wlo + 139264;

  // --- prep: pre-split x and all weights ---
  split_x_kernel<<<(int)((N64 + 1023) / 1024), 256, 0, stream>>>(x, xhi, xlo, (int)N64);
  split_w_kernel<<<144, 256, 0, stream>>>(g1Wl, g1Wr, g2Wl, g2Wr, g3Wl, g3Wr,
                                          t2W, d1W, d2Wl, d2Wr, d3Wl, d3Wr, Whi, Wlo);

  // --- CSR build: ONE fused atomic pass into padded slab + inv ---
  hipMemsetAsync(cnt, 0, (size_t)N * sizeof(int), stream);
  place_pad_kernel<<<(E + 255) / 256, 256, 0, stream>>>(src, dst, cnt, esp, E);
  inv_kernel<<<(N + 255) / 256, 256, 0, stream>>>(cnt, inv, N);

  // ggn1: x(64) -> act1 s16, tanh  [A = exact x split; mean = pair]
  gather_f32s_kernel<<<GB, 256, 0, stream>>>(x, esp, cnt, inv, Mhi, Mlo, N);
  node_mfma_kernel<64, 128, ACT_TANH, true, false, true, 2, false, 0, 0><<<NB, 512, 0, stream>>>(
      xhi, xlo, Mhi, Mlo, W_g1Wr_h, W_g1Wr_l, W_g1Wl_h, W_g1Wl_l, g1b, nullptr,
      nullptr, nullptr, act1, nullptr, nullptr, N);

  // ggn2: act1 -> act2 s16, tanh  [s16 gather -> s16 mean; s16 A]
  gather_s16_kernel<<<GB, 256, 0, stream>>>(act1, esp, cnt, inv, Ms16, N);
  node_mfma_kernel<128, 128, ACT_TANH, true, false, true, 2, false, 2, 2><<<NB, 512, 0, stream>>>(
      (const __bf16*)act1, nullptr, (const __bf16*)Ms16, nullptr,
      W_g2Wr_h, W_g2Wr_l, W_g2Wl_h, W_g2Wl_l,
      g2b, nullptr, nullptr, nullptr, act2, nullptr, nullptr, N);

  // ggn3: act2 -> act1 s16, tanh  [s16 gather -> s16 mean; s16 A]
  gather_s16_kernel<<<GB, 256, 0, stream>>>(act2, esp, cnt, inv, Ms16, N);
  node_mfma_kernel<128, 128, ACT_TANH, true, false, true, 2, false, 2, 2><<<NB, 512, 0, stream>>>(
      (const __bf16*)act2, nullptr, (const __bf16*)Ms16, nullptr,
      W_g3Wr_h, W_g3Wr_l, W_g3Wl_h, W_g3Wl_l,
      g3b, nullptr, nullptr, nullptr, act1, nullptr, nullptr, N);

  // tr2: act1(128, s16) -> mu(64) fp32 + lv fp32 + split(muhi/mulo)
  node_mfma_kernel<128, 64, ACT_NONE, false, false, true, 0, true, 2, 0><<<NB, 512, 0, stream>>>(
      (const __bf16*)act1, nullptr, nullptr, nullptr, W_t2W_h, W_t2W_l, nullptr, nullptr,
      t2b, nullptr, mu, lv, nullptr, muhi, mulo, N);

  // dec1: mu(64) -> shB fp16 ONLY, leaky
  node_mfma_kernel<64, 128, ACT_LEAKY, false, false, true, 1, false, 0, 0><<<NB, 512, 0, stream>>>(
      muhi, mulo, nullptr, nullptr, W_d1W_h, W_d1W_l, nullptr, nullptr, d1b, nullptr,
      nullptr, nullptr, shB, nullptr, nullptr, N);

  // dec2: A = shB fp16 (ASRC=1); mean = pair; out -> shA fp16 ONLY, leaky
  gather_h128_kernel<<<GB, 256, 0, stream>>>(shB, esp, cnt, inv, Mhi, Mlo, N);
  node_mfma_kernel<128, 128, ACT_LEAKY, true, false, true, 1, false, 1, 0><<<NB, 512, 0, stream>>>(
      (const __bf16*)shB, nullptr, Mhi, Mlo, W_d2Wr_h, W_d2Wr_l, W_d2Wl_h, W_d2Wl_l,
      d2b, nullptr, nullptr, nullptr, shA, nullptr, nullptr, N);

  // dec3 (linearity): shC = fp16(shA@Wl^T); gather -> meanF;
  // hBf = tanh(meanF + shA@Wr + b)
  node_mfma_kernel<128, 64, ACT_NONE, false, false, false, 1, false, 1, 0><<<NB, 512, 0, stream>>>(
      (const __bf16*)shA, nullptr, nullptr, nullptr, W_d3Wl_h, W_d3Wl_l, nullptr, nullptr,
      nullptr, nullptr, nullptr, nullptr, shC, nullptr, nullptr, N);
  gather_h64_kernel<<<GB, 256, 0, stream>>>(shC, esp, cnt, inv, meanF, N);
  node_mfma_kernel<128, 64, ACT_TANH, false, true, true, 0, false, 1, 0><<<NB, 512, 0, stream>>>(
      (const __bf16*)shA, nullptr, nullptr, nullptr, W_d3Wr_h, W_d3Wr_l, nullptr, nullptr,
      d3b, meanF, hBf, nullptr, nullptr, nullptr, nullptr, N);

  // dec4 (linearity, fp32): y4 = hBf@Wl^T (3-pad-4); gather4; out = mean4 + b + hBf@Wr
  dec4_pre_kernel<<<GB, 256, 0, stream>>>(hBf, d4Wl, y4, N);
  gather_mean4_kernel<<<(N + 255) / 256, 256, 0, stream>>>(y4, esp, cnt, inv, mean4, N);
  dec4_final_kernel<<<GB, 256, 0, stream>>>(hBf, mean4, d4Wr, d4b, out, N);
}

// Round 12
// 874.301 us; speedup vs baseline: 1.0257x; 1.0257x over previous
//
#include <hip/hip_runtime.h>
#include <cmath>

// ---------------------------------------------------------------------------
// GCN_Message: graph VAE forward. Round 21 (= R19 CSR + R20 s16 means +
// fp16 dec2 mean):
//   - R20 fused padded-slab CSR REGRESSED (138us vs 103): the scatter-write
//     depends on the atomic return -> latencies serialize. Reverted to R19's
//     count_rank(coalesced rank write) + hierarchical scan + scatter.
//   - KEPT from R20: ggn2/ggn3 means as s16 Q15 (passed; absmax improved to
//     9.77e-4). NEW: dec2 mean as fp16 single (MSRC=1) - mean of already-
//     fp16 gather inputs, same validated error class; saves ~51MB.
//   - Decoder fp16 A-path (R19). GEMM: 512-thd BM=256 (R17), W-persistent
//     LDS (R16). Encoder acts s16 (R14). 3-term split-bf16 MFMA (R6).
// ---------------------------------------------------------------------------

constexpr int ACT_NONE = 0, ACT_TANH = 1, ACT_LEAKY = 2;
constexpr int SCAN_CHUNK = 4096;  // 1024 threads x 4 items

typedef __attribute__((ext_vector_type(8))) __bf16 bf16x8;
typedef __attribute__((ext_vector_type(4))) float f32x4;
typedef __attribute__((ext_vector_type(4))) unsigned short u16x4;
typedef __attribute__((ext_vector_type(8))) unsigned short u16x8;

__device__ __forceinline__ unsigned short f2h(float x) {
  _Float16 h = (_Float16)x;
  unsigned short u;
  __builtin_memcpy(&u, &h, 2);
  return u;
}
__device__ __forceinline__ float h2f(unsigned short s) {
  _Float16 h;
  __builtin_memcpy(&h, &s, 2);
  return (float)h;
}
__device__ __forceinline__ float hlo(unsigned int u) {
  return h2f((unsigned short)(u & 0xffffu));
}
__device__ __forceinline__ float hhi(unsigned int u) {
  return h2f((unsigned short)(u >> 16));
}
__device__ __forceinline__ void split_bf16(float x, __bf16& h, __bf16& l) {
  h = (__bf16)x;
  l = (__bf16)(x - (float)h);
}
__device__ __forceinline__ unsigned short b2u(__bf16 b) {
  unsigned short u;
  __builtin_memcpy(&u, &b, 2);
  return u;
}

// elementwise split: fp32 -> bf16 hi/lo (total % 4 == 0)
__global__ __launch_bounds__(256) void split_x_kernel(const float* __restrict__ in,
                                                      __bf16* __restrict__ hi,
                                                      __bf16* __restrict__ lo, int total) {
  int i = (blockIdx.x * 256 + threadIdx.x) * 4;
  if (i >= total) return;
  float4 v = *(const float4*)(in + i);
  float vv[4] = {v.x, v.y, v.z, v.w};
  u16x4 h, l;
#pragma unroll
  for (int j = 0; j < 4; ++j) {
    __bf16 hb, lb;
    split_bf16(vv[j], hb, lb);
    h[j] = b2u(hb);
    l[j] = b2u(lb);
  }
  *(u16x4*)(hi + i) = h;
  *(u16x4*)(lo + i) = l;
}

// one-shot split of all 12 GEMM weight matrices into Whi/Wlo at fixed offsets
__global__ __launch_bounds__(256) void split_w_kernel(
    const float* p0, const float* p1, const float* p2, const float* p3,
    const float* p4, const float* p5, const float* p6, const float* p7,
    const float* p8, const float* p9, const float* p10, const float* p11,
    __bf16* __restrict__ hi, __bf16* __restrict__ lo) {
  int b = blockIdx.x;
  const float* src;
  int boff, doff;
  if      (b < 8)   { src = p0;  boff = b;       doff = 0; }
  else if (b < 16)  { src = p1;  boff = b - 8;   doff = 8192; }
  else if (b < 32)  { src = p2;  boff = b - 16;  doff = 16384; }
  else if (b < 48)  { src = p3;  boff = b - 32;  doff = 32768; }
  else if (b < 64)  { src = p4;  boff = b - 48;  doff = 49152; }
  else if (b < 80)  { src = p5;  boff = b - 64;  doff = 65536; }
  else if (b < 88)  { src = p6;  boff = b - 80;  doff = 81920; }
  else if (b < 96)  { src = p7;  boff = b - 88;  doff = 90112; }
  else if (b < 112) { src = p8;  boff = b - 96;  doff = 98304; }
  else if (b < 128) { src = p9;  boff = b - 112; doff = 114688; }
  else if (b < 136) { src = p10; boff = b - 128; doff = 131072; }
  else              { src = p11; boff = b - 136; doff = 139264; }
  int i = boff * 1024 + threadIdx.x * 4;
  float4 v = *(const float4*)(src + i);
  float vv[4] = {v.x, v.y, v.z, v.w};
  u16x4 h, l;
#pragma unroll
  for (int j = 0; j < 4; ++j) {
    __bf16 hb, lb;
    split_bf16(vv[j], hb, lb);
    h[j] = b2u(hb);
    l[j] = b2u(lb);
  }
  *(u16x4*)(hi + doff + i) = h;
  *(u16x4*)(lo + doff + i) = l;
}

// pass 1: rank[e] = within-segment index; cnt accumulates degrees
__global__ __launch_bounds__(256) void count_rank_kernel(const int* __restrict__ dst,
                                                         int* __restrict__ cnt,
                                                         int* __restrict__ rank, int E) {
  int e = blockIdx.x * 256 + threadIdx.x;
  if (e < E) rank[e] = atomicAdd(&cnt[dst[e]], 1);
}

// scan phase A: per-block (4096-elem) exclusive scan -> rowptr (local),
// block total -> bsum; also inv = 1/max(cnt,1)
__global__ __launch_bounds__(1024) void scan_blk_kernel(const int* __restrict__ cnt,
                                                        int* __restrict__ rowptr,
                                                        float* __restrict__ inv,
                                                        int* __restrict__ bsum, int n) {
  __shared__ int wsum[17];
  const int lane = threadIdx.x & 63;
  const int wid = threadIdx.x >> 6;
  const int i0 = blockIdx.x * SCAN_CHUNK + threadIdx.x * 4;
  int v[4];
  if (i0 + 3 < n) {
    int4 t = *(const int4*)(cnt + i0);
    v[0] = t.x; v[1] = t.y; v[2] = t.z; v[3] = t.w;
  } else {
#pragma unroll
    for (int j = 0; j < 4; ++j) v[j] = (i0 + j < n) ? cnt[i0 + j] : 0;
  }
#pragma unroll
  for (int j = 0; j < 4; ++j)
    if (i0 + j < n) inv[i0 + j] = 1.0f / (float)(v[j] > 1 ? v[j] : 1);
  const int s = v[0] + v[1] + v[2] + v[3];
  int x = s;
#pragma unroll
  for (int off = 1; off < 64; off <<= 1) {
    int t = __shfl_up(x, off);
    if (lane >= off) x += t;
  }
  if (lane == 63) wsum[wid + 1] = x;
  __syncthreads();
  if (threadIdx.x == 0) {
    wsum[0] = 0;
    for (int w = 1; w <= 16; ++w) wsum[w] += wsum[w - 1];
    bsum[blockIdx.x] = wsum[16];
  }
  __syncthreads();
  int p = wsum[wid] + x - s;
#pragma unroll
  for (int j = 0; j < 4; ++j) {
    if (i0 + j < n) rowptr[i0 + j] = p;
    p += v[j];
  }
}

// scan phase B: one block exclusive-scans bsum[nb] in place (nb <= 1024);
// grand total -> rowptr[n]
__global__ __launch_bounds__(1024) void scan_sums_kernel(int* __restrict__ bsum,
                                                         int* __restrict__ rowptr,
                                                         int nb, int n) {
  __shared__ int wsum[17];
  const int lane = threadIdx.x & 63;
  const int wid = threadIdx.x >> 6;
  const int v = (threadIdx.x < nb) ? bsum[threadIdx.x] : 0;
  int x = v;
#pragma unroll
  for (int off = 1; off < 64; off <<= 1) {
    int t = __shfl_up(x, off);
    if (lane >= off) x += t;
  }
  if (lane == 63) wsum[wid + 1] = x;
  __syncthreads();
  if (threadIdx.x == 0) {
    wsum[0] = 0;
    for (int w = 1; w <= 16; ++w) wsum[w] += wsum[w - 1];
    rowptr[n] = wsum[16];
  }
  __syncthreads();
  if (threadIdx.x < nb) bsum[threadIdx.x] = wsum[wid] + x - v;
}

// scan phase C: add block offset back into rowptr
__global__ __launch_bounds__(1024) void scan_add_kernel(int* __restrict__ rowptr,
                                                        const int* __restrict__ bsum,
                                                        int n) {
  const int off = bsum[blockIdx.x];
  const int i0 = blockIdx.x * SCAN_CHUNK + threadIdx.x * 4;
  if (i0 + 3 < n) {
    int4 t = *(const int4*)(rowptr + i0);
    t.x += off; t.y += off; t.z += off; t.w += off;
    *(int4*)(rowptr + i0) = t;
  } else {
    for (int j = 0; j < 4; ++j)
      if (i0 + j < n) rowptr[i0 + j] += off;
  }
}

// pass 2: atomic-free scatter
__global__ __launch_bounds__(256) void scatter_kernel(const int* __restrict__ src,
                                                      const int* __restrict__ dst,
                                                      const int* __restrict__ rowptr,
                                                      const int* __restrict__ rank,
                                                      int* __restrict__ esrc, int E) {
  int e = blockIdx.x * 256 + threadIdx.x;
  if (e < E) esrc[rowptr[dst[e]] + rank[e]] = src[e];
}

// fp32 gather (ggn1, D=64 from x): wave per node; writes split bf16 mean
__global__ __launch_bounds__(256) void gather_f32s_kernel(
    const float* __restrict__ in, const int* __restrict__ esrc,
    const int* __restrict__ rowptr, const float* __restrict__ inv,
    __bf16* __restrict__ Mhi, __bf16* __restrict__ Mlo, int n) {
  const int node = blockIdx.x * 4 + (threadIdx.x >> 6);
  const int lane = threadIdx.x & 63;
  if (node >= n) return;
  const int beg = rowptr[node];
  const int end = rowptr[node + 1];
  const float iv = inv[node];
  float a0 = 0.f, a1 = 0.f, a2 = 0.f, a3 = 0.f;
  for (int b = beg; b < end; b += 64) {
    int m = end - b;
    if (m > 64) m = 64;
    int myi = (lane < m) ? esrc[b + lane] : 0;
    int s = 0;
    for (; s + 4 <= m; s += 4) {
      int i0 = __shfl(myi, s);
      int i1 = __shfl(myi, s + 1);
      int i2 = __shfl(myi, s + 2);
      int i3 = __shfl(myi, s + 3);
      a0 += in[(size_t)i0 * 64 + lane];
      a1 += in[(size_t)i1 * 64 + lane];
      a2 += in[(size_t)i2 * 64 + lane];
      a3 += in[(size_t)i3 * 64 + lane];
    }
    for (; s < m; ++s) {
      int i0 = __shfl(myi, s);
      a0 += in[(size_t)i0 * 64 + lane];
    }
  }
  float mv = ((a0 + a1) + (a2 + a3)) * iv;
  __bf16 h, l;
  split_bf16(mv, h, l);
  Mhi[(size_t)node * 64 + lane] = h;
  Mlo[(size_t)node * 64 + lane] = l;
}

// int16 Q1.15 gather (encoder ggn2/ggn3): EXACT int32 neighbor sum;
// mean emitted as s16 Q15 (means of Q15 values are in [-1,1]).
__global__ __launch_bounds__(256) void gather_s16_kernel(
    const unsigned short* __restrict__ inq, const int* __restrict__ esrc,
    const int* __restrict__ rowptr, const float* __restrict__ inv,
    unsigned short* __restrict__ Ms, int n) {
  const int node = blockIdx.x * 4 + (threadIdx.x >> 6);
  const int lane = threadIdx.x & 63;
  if (node >= n) return;
  const int beg = rowptr[node];
  const int end = rowptr[node + 1];
  const float iv = inv[node];
  const unsigned int* bu = (const unsigned int*)inq;
  int a0l = 0, a0h = 0, a1l = 0, a1h = 0;
  int a2l = 0, a2h = 0, a3l = 0, a3h = 0;
  for (int b = beg; b < end; b += 64) {
    int m = end - b;
    if (m > 64) m = 64;
    int myi = (lane < m) ? esrc[b + lane] : 0;
    int s = 0;
    for (; s + 4 <= m; s += 4) {
      int i0 = __shfl(myi, s);
      int i1 = __shfl(myi, s + 1);
      int i2 = __shfl(myi, s + 2);
      int i3 = __shfl(myi, s + 3);
      unsigned int u0 = bu[(size_t)i0 * 64 + lane];
      unsigned int u1 = bu[(size_t)i1 * 64 + lane];
      unsigned int u2 = bu[(size_t)i2 * 64 + lane];
      unsigned int u3 = bu[(size_t)i3 * 64 + lane];
      a0l += (int)(short)u0; a0h += ((int)u0) >> 16;
      a1l += (int)(short)u1; a1h += ((int)u1) >> 16;
      a2l += (int)(short)u2; a2h += ((int)u2) >> 16;
      a3l += (int)(short)u3; a3h += ((int)u3) >> 16;
    }
    for (; s < m; ++s) {
      int i0 = __shfl(myi, s);
      unsigned int u0 = bu[(size_t)i0 * 64 + lane];
      a0l += (int)(short)u0; a0h += ((int)u0) >> 16;
    }
  }
  float sx = (float)((a0l + a1l) + (a2l + a3l)) * iv;
  float sy = (float)((a0h + a1h) + (a2h + a3h)) * iv;
  short qx = (short)__builtin_rintf(sx);
  short qy = (short)__builtin_rintf(sy);
  ((unsigned int*)Ms)[(size_t)node * 64 + lane] =
      (unsigned int)(unsigned short)qx | ((unsigned int)(unsigned short)qy << 16);
}

// fp16 gather, D=128 (dec2): wave per node; mean emitted as fp16 single
__global__ __launch_bounds__(256) void gather_h128_kernel(
    const unsigned short* __restrict__ inh, const int* __restrict__ esrc,
    const int* __restrict__ rowptr, const float* __restrict__ inv,
    unsigned short* __restrict__ Mh, int n) {
  const int node = blockIdx.x * 4 + (threadIdx.x >> 6);
  const int lane = threadIdx.x & 63;
  if (node >= n) return;
  const int beg = rowptr[node];
  const int end = rowptr[node + 1];
  const float iv = inv[node];
  const unsigned int* bu = (const unsigned int*)inh;
  float a0x = 0.f, a0y = 0.f, a1x = 0.f, a1y = 0.f;
  float a2x = 0.f, a2y = 0.f, a3x = 0.f, a3y = 0.f;
  for (int b = beg; b < end; b += 64) {
    int m = end - b;
    if (m > 64) m = 64;
    int myi = (lane < m) ? esrc[b + lane] : 0;
    int s = 0;
    for (; s + 4 <= m; s += 4) {
      int i0 = __shfl(myi, s);
      int i1 = __shfl(myi, s + 1);
      int i2 = __shfl(myi, s + 2);
      int i3 = __shfl(myi, s + 3);
      unsigned int u0 = bu[(size_t)i0 * 64 + lane];
      unsigned int u1 = bu[(size_t)i1 * 64 + lane];
      unsigned int u2 = bu[(size_t)i2 * 64 + lane];
      unsigned int u3 = bu[(size_t)i3 * 64 + lane];
      a0x += hlo(u0); a0y += hhi(u0);
      a1x += hlo(u1); a1y += hhi(u1);
      a2x += hlo(u2); a2y += hhi(u2);
      a3x += hlo(u3); a3y += hhi(u3);
    }
    for (; s < m; ++s) {
      int i0 = __shfl(myi, s);
      unsigned int u0 = bu[(size_t)i0 * 64 + lane];
      a0x += hlo(u0); a0y += hhi(u0);
    }
  }
  float rx = ((a0x + a1x) + (a2x + a3x)) * iv;
  float ry = ((a0y + a1y) + (a2y + a3y)) * iv;
  ((unsigned int*)Mh)[(size_t)node * 64 + lane] =
      (unsigned int)f2h(rx) | ((unsigned int)f2h(ry) << 16);
}

// fp16 gather, D=64 (dec3): half-wave per neighbor-pair member; fp32 out
__global__ __launch_bounds__(256) void gather_h64_kernel(
    const unsigned short* __restrict__ inh, const int* __restrict__ esrc,
    const int* __restrict__ rowptr, const float* __restrict__ inv,
    float* __restrict__ meanb, int n) {
  const int node = blockIdx.x * 4 + (threadIdx.x >> 6);
  const int lane = threadIdx.x & 63;
  if (node >= n) return;
  const int beg = rowptr[node];
  const int end = rowptr[node + 1];
  const float iv = inv[node];
  const unsigned int* bu = (const unsigned int*)inh;
  const int half = lane >> 5;
  const int hl = lane & 31;
  float ax = 0.f, ay = 0.f, bx = 0.f, by = 0.f;
  for (int b = beg; b < end; b += 64) {
    int m = end - b;
    if (m > 64) m = 64;
    int myi = (lane < m) ? esrc[b + lane] : 0;
    int s = 0;
    for (; s + 4 <= m; s += 4) {
      int i0 = __shfl(myi, s + half);
      int i1 = __shfl(myi, s + 2 + half);
      unsigned int u0 = bu[(size_t)i0 * 32 + hl];
      unsigned int u1 = bu[(size_t)i1 * 32 + hl];
      ax += hlo(u0); ay += hhi(u0);
      bx += hlo(u1); by += hhi(u1);
    }
    for (; s < m; s += 2) {
      int t = s + half;
      if (t < m) {
        int i0 = __shfl(myi, t);
        unsigned int u0 = bu[(size_t)i0 * 32 + hl];
        ax += hlo(u0); ay += hhi(u0);
      }
    }
  }
  float sx = ax + bx, sy = ay + by;
  sx += __shfl_xor(sx, 32);
  sy += __shfl_xor(sy, 32);
  if (half == 0)
    ((float2*)meanb)[(size_t)node * 32 + hl] = make_float2(sx * iv, sy * iv);
}

// thread per node: mean over 4-wide (padded float4) rows
__global__ __launch_bounds__(256) void gather_mean4_kernel(
    const float* __restrict__ y4, const int* __restrict__ esrc,
    const int* __restrict__ rowptr, const float* __restrict__ inv,
    float* __restrict__ mean4, int n) {
  int i = blockIdx.x * 256 + threadIdx.x;
  if (i >= n) return;
  const int beg = rowptr[i], end = rowptr[i + 1];
  const float iv = inv[i];
  float sx = 0.f, sy = 0.f, sz = 0.f;
  const float4* b = (const float4*)y4;
  for (int j = beg; j < end; ++j) {
    float4 v = b[esrc[j]];
    sx += v.x; sy += v.y; sz += v.z;
  }
  ((float4*)mean4)[i] = make_float4(sx * iv, sy * iv, sz * iv, 0.f);
}

// out[row,col] = act( (AGG ? mean@Wl^T : 0) + (ADDMEAN ? meanF : 0)
//                     + in@Wr^T + (BIAS ? b : 0) )
// 512-thread blocks (8 waves), BM=256; W panel persists in LDS per phase
// (row stride DI+8); A streamed global->VGPR, k-loop fully unrolled.
// ASRC/MSRC: 0 = bf16 hi/lo pair; 1 = fp16 single; 2 = s16 Q1.15 (1/2
// converted+split in VGPRs). ASRC applies to phase 0 (A), MSRC to phase 1
// (mean; pointer Mhi reinterpreted when MSRC != 0).
template <int DI, int DO, int ACT, bool AGG, bool ADDMEAN, bool BIAS, int SH,
          bool OSPLIT, int ASRC, int MSRC>
__global__ __launch_bounds__(512) void node_mfma_kernel(
    const __bf16* __restrict__ Ahi, const __bf16* __restrict__ Alo,
    const __bf16* __restrict__ Mhi, const __bf16* __restrict__ Mlo,
    const __bf16* __restrict__ Wrhi, const __bf16* __restrict__ Wrlo,
    const __bf16* __restrict__ Wlhi, const __bf16* __restrict__ Wllo,
    const float* __restrict__ bias, const float* __restrict__ meanF,
    float* __restrict__ out, float* __restrict__ out2,
    unsigned short* __restrict__ outh,
    __bf16* __restrict__ ohi, __bf16* __restrict__ olo, int n) {
  constexpr int BM = 256;
  constexpr int KSW = DI + 8;
  constexpr int CT = DO / 16;
  constexpr int EL = DO * DI / 512;
  __shared__ __align__(16) __bf16 Ws_hi[DO * KSW];
  __shared__ __align__(16) __bf16 Ws_lo[DO * KSW];

  const int wv = threadIdx.x >> 6;
  const int lane = threadIdx.x & 63;
  const int lm = lane & 15;
  const int lq = lane >> 4;
  const int row0 = blockIdx.x * BM;

  f32x4 acc[2][CT];
#pragma unroll
  for (int rt = 0; rt < 2; ++rt)
#pragma unroll
    for (int ct = 0; ct < CT; ++ct) acc[rt][ct] = (f32x4){0.f, 0.f, 0.f, 0.f};

  bf16x8 zf;
#pragma unroll
  for (int j = 0; j < 8; ++j) zf[j] = (__bf16)0.f;

  const int rA0 = row0 + wv * 32 + lm;
  const int rA1 = rA0 + 16;
  const bool ok0 = rA0 < n;
  const bool ok1 = rA1 < n;
  const int kofs = lq * 8;

  const int sc = (threadIdx.x * EL) / DI;
  const int sk = (threadIdx.x * EL) % DI;

  const int nphase = AGG ? 2 : 1;
#pragma unroll
  for (int phase = 0; phase < nphase; ++phase) {
    const __bf16* WH = (phase == 0) ? Wrhi : Wlhi;
    const __bf16* WL = (phase == 0) ? Wrlo : Wllo;
    if (phase > 0) __syncthreads();
#pragma unroll
    for (int j = 0; j < EL / 8; ++j) {
      *(bf16x8*)(&Ws_hi[sc * KSW + sk + j * 8]) =
          *(const bf16x8*)(WH + (size_t)sc * DI + sk + j * 8);
      *(bf16x8*)(&Ws_lo[sc * KSW + sk + j * 8]) =
          *(const bf16x8*)(WL + (size_t)sc * DI + sk + j * 8);
    }
    __syncthreads();

    const __bf16* AH = (phase == 0) ? Ahi : Mhi;
    const __bf16* AL = (phase == 0) ? Alo : Mlo;
    const int code = (phase == 0) ? ASRC : MSRC;
#pragma unroll
    for (int k0 = 0; k0 < DI; k0 += 32) {
      bf16x8 ah[2], al[2];
      if (code != 0) {
        // u16-coded A (fp16 or s16 Q1.15): load 8 shorts/row, convert+split
        const unsigned short* Q = (const unsigned short*)AH;
        u16x8 q0, q1;
        if (ok0) q0 = *(const u16x8*)(Q + (size_t)rA0 * DI + k0 + kofs);
        else {
#pragma unroll
          for (int j = 0; j < 8; ++j) q0[j] = 0;
        }
        if (ok1) q1 = *(const u16x8*)(Q + (size_t)rA1 * DI + k0 + kofs);
        else {
#pragma unroll
          for (int j = 0; j < 8; ++j) q1[j] = 0;
        }
#pragma unroll
        for (int j = 0; j < 8; ++j) {
          float v0, v1;
          if (code == 1) {
            v0 = h2f(q0[j]);
            v1 = h2f(q1[j]);
          } else {
            v0 = (float)(short)q0[j] * (1.0f / 32767.0f);
            v1 = (float)(short)q1[j] * (1.0f / 32767.0f);
          }
          __bf16 hb, lb;
          split_bf16(v0, hb, lb);
          ah[0][j] = hb; al[0][j] = lb;
          split_bf16(v1, hb, lb);
          ah[1][j] = hb; al[1][j] = lb;
        }
      } else {
        ah[0] = ok0 ? *(const bf16x8*)(AH + (size_t)rA0 * DI + k0 + kofs) : zf;
        al[0] = ok0 ? *(const bf16x8*)(AL + (size_t)rA0 * DI + k0 + kofs) : zf;
        ah[1] = ok1 ? *(const bf16x8*)(AH + (size_t)rA1 * DI + k0 + kofs) : zf;
        al[1] = ok1 ? *(const bf16x8*)(AL + (size_t)rA1 * DI + k0 + kofs) : zf;
      }
#pragma unroll
      for (int ct = 0; ct < CT; ++ct) {
        const int c = ct * 16 + lm;
        bf16x8 bh = *(const bf16x8*)(&Ws_hi[c * KSW + k0 + kofs]);
        bf16x8 bl = *(const bf16x8*)(&Ws_lo[c * KSW + k0 + kofs]);
#pragma unroll
        for (int rt = 0; rt < 2; ++rt) {
          acc[rt][ct] = __builtin_amdgcn_mfma_f32_16x16x32_bf16(ah[rt], bh, acc[rt][ct], 0, 0, 0);
          acc[rt][ct] = __builtin_amdgcn_mfma_f32_16x16x32_bf16(al[rt], bh, acc[rt][ct], 0, 0, 0);
          acc[rt][ct] = __builtin_amdgcn_mfma_f32_16x16x32_bf16(ah[rt], bl, acc[rt][ct], 0, 0, 0);
        }
      }
    }
  }

#pragma unroll
  for (int rt = 0; rt < 2; ++rt)
#pragma unroll
    for (int ct = 0; ct < CT; ++ct) {
      const int col = ct * 16 + lm;
      const float bval = BIAS ? bias[col] : 0.f;
      f32x4 a = acc[rt][ct];
#pragma unroll
      for (int r = 0; r < 4; ++r) {
        const int row = row0 + wv * 32 + rt * 16 + lq * 4 + r;
        if (row < n) {
          float t = a[r] + bval;
          if (ADDMEAN) t += meanF[(size_t)row * DO + col];
          if (ACT == ACT_TANH) t = tanhf(t);
          else if (ACT == ACT_LEAKY) t = (t > 0.f) ? t : 0.01f * t;
          if (out) out[(size_t)row * DO + col] = t;
          if (out2) out2[(size_t)row * DO + col] = t;
          if constexpr (SH == 1) {
            if (outh) outh[(size_t)row * DO + col] = f2h(t);
          } else if constexpr (SH == 2) {
            if (outh)
              outh[(size_t)row * DO + col] =
                  (unsigned short)(short)__builtin_rintf(t * 32767.0f);
          }
          if constexpr (OSPLIT) {
            __bf16 hb, lb;
            split_bf16(t, hb, lb);
            ohi[(size_t)row * DO + col] = hb;
            olo[(size_t)row * DO + col] = lb;
          }
        }
      }
    }
}

// y4[node] = hB[node] @ Wl^T (3 outputs, padded float4); wave per node
__global__ __launch_bounds__(256) void dec4_pre_kernel(
    const float* __restrict__ hB, const float* __restrict__ Wl,
    float* __restrict__ y4, int n) {
  const int node = blockIdx.x * 4 + (threadIdx.x >> 6);
  const int lane = threadIdx.x & 63;
  if (node >= n) return;
  float v = hB[(size_t)node * 64 + lane];
  float p0 = v * Wl[lane];
  float p1 = v * Wl[64 + lane];
  float p2 = v * Wl[128 + lane];
#pragma unroll
  for (int off = 32; off >= 1; off >>= 1) {
    p0 += __shfl_xor(p0, off);
    p1 += __shfl_xor(p1, off);
    p2 += __shfl_xor(p2, off);
  }
  if (lane == 0) ((float4*)y4)[node] = make_float4(p0, p1, p2, 0.f);
}

// out = mean4 + b + hB@Wr^T, scattered layout (z2[:,:2], z2[:,2]); wave/node
__global__ __launch_bounds__(256) void dec4_final_kernel(
    const float* __restrict__ hB, const float* __restrict__ mean4,
    const float* __restrict__ Wr, const float* __restrict__ bias,
    float* __restrict__ out, int n) {
  const int node = blockIdx.x * 4 + (threadIdx.x >> 6);
  const int lane = threadIdx.x & 63;
  if (node >= n) return;
  float v = hB[(size_t)node * 64 + lane];
  float p0 = v * Wr[lane];
  float p1 = v * Wr[64 + lane];
  float p2 = v * Wr[128 + lane];
#pragma unroll
  for (int off = 32; off >= 1; off >>= 1) {
    p0 += __shfl_xor(p0, off);
    p1 += __shfl_xor(p1, off);
    p2 += __shfl_xor(p2, off);
  }
  if (lane == 0) {
    float4 m = ((const float4*)mean4)[node];
    out[2 * (size_t)node]     = p0 + m.x + bias[0];
    out[2 * (size_t)node + 1] = p1 + m.y + bias[1];
    out[2 * (size_t)n + node] = p2 + m.z + bias[2];
  }
}

extern "C" void kernel_launch(void* const* d_in, const int* in_sizes, int n_in,
                              void* d_out, int out_size, void* d_ws, size_t ws_size,
                              hipStream_t stream) {
  const float* x = (const float*)d_in[0];
  const int* ei = (const int*)d_in[1];
  const int N = in_sizes[0] / 64;
  const int E = in_sizes[1] / 2;
  const int* src = ei;
  const int* dst = ei + E;
  const float* g1Wl = (const float*)d_in[2];
  const float* g1b  = (const float*)d_in[3];
  const float* g1Wr = (const float*)d_in[4];
  const float* g2Wl = (const float*)d_in[5];
  const float* g2b  = (const float*)d_in[6];
  const float* g2Wr = (const float*)d_in[7];
  const float* g3Wl = (const float*)d_in[8];
  const float* g3b  = (const float*)d_in[9];
  const float* g3Wr = (const float*)d_in[10];
  const float* t2W  = (const float*)d_in[11];
  const float* t2b  = (const float*)d_in[12];
  const float* d1W  = (const float*)d_in[13];
  const float* d1b  = (const float*)d_in[14];
  const float* d2Wl = (const float*)d_in[15];
  const float* d2b  = (const float*)d_in[16];
  const float* d2Wr = (const float*)d_in[17];
  const float* d3Wl = (const float*)d_in[18];
  const float* d3b  = (const float*)d_in[19];
  const float* d3Wr = (const float*)d_in[20];
  const float* d4Wl = (const float*)d_in[21];
  const float* d4b  = (const float*)d_in[22];
  const float* d4Wr = (const float*)d_in[23];

  const size_t N64 = (size_t)N * 64;
  const size_t N128 = (size_t)N * 128;

  char* w = (char*)d_ws;
  auto alloc = [&](size_t bytes) {
    char* p = w;
    w += (bytes + 255) & ~(size_t)255;
    return p;
  };
  __bf16* Ahi = (__bf16*)alloc(N128 * 2);   // enc act1 s16; dec2-out shA fp16
  __bf16* Alo = (__bf16*)alloc(N128 * 2);   // enc act2 s16
  float*  meanF = (float*)alloc(N128 * 4);  // aliased below
  __bf16* xhi = (__bf16*)alloc(N64 * 2);    // also muhi, also shC
  __bf16* xlo = (__bf16*)alloc(N64 * 2);    // also mulo
  __bf16* Whi = (__bf16*)alloc(147456 * 2);
  __bf16* Wlo = (__bf16*)alloc(147456 * 2);
  int*    cnt = (int*)alloc((size_t)N * 4);
  float*  inv = (float*)alloc((size_t)N * 4);
  int*    rowp = (int*)alloc(((size_t)N + 1) * 4);
  int*    rank = (int*)alloc((size_t)E * 4);
  int*    esrc = (int*)alloc((size_t)E * 4);
  unsigned short* shB = (unsigned short*)alloc(N128 * 2);  // dec1 out fp16

  // encoder s16 activation buffers (alias Ahi/Alo; dead before decoder use)
  unsigned short* act1 = (unsigned short*)Ahi;  // ggn1 out; ggn2 in; ggn3 out; tr2 A
  unsigned short* act2 = (unsigned short*)Alo;  // ggn2 out; ggn3 in
  unsigned short* shA = (unsigned short*)Ahi;   // dec2 out fp16 (act1 dead after tr2)

  // aliases of meanF (disjoint lifetimes):
  __bf16* Mhi = (__bf16*)meanF;        // pair mean (ggn1)
  __bf16* Mlo = Mhi + N128;
  unsigned short* Ms16 = (unsigned short*)meanF;  // s16 mean (ggn2/ggn3)
  unsigned short* Mh16 = (unsigned short*)meanF;  // fp16 mean (dec2)
  int*    bsum = (int*)meanF;          // scan block sums (CSR build only)
  float*  y4 = meanF;                  // N x 4 (dec4)
  float*  mean4 = meanF + 4 * (size_t)N;
  float*  hBf = meanF + N64;           // N x 64 f32 (dec3 out -> dec4)
  // aliases of xhi/xlo:
  __bf16* muhi = xhi;
  __bf16* mulo = xlo;
  unsigned short* shC = (unsigned short*)xhi;

  float* out = (float*)d_out;
  float* mu  = out + 3 * (size_t)N;  // N x 64
  float* lv  = mu + 64 * (size_t)N;  // N x 64 (logvar == mu)

  const int NB = (N + 255) / 256;  // 512-thread GEMM blocks, BM=256
  const int GB = (N + 3) / 4;
  const int SB = (N + SCAN_CHUNK - 1) / SCAN_CHUNK;

  // weight split offsets (bf16 elems) in Whi/Wlo
  const __bf16 *W_g1Wl_h = Whi + 0,      *W_g1Wl_l = Wlo + 0;
  const __bf16 *W_g1Wr_h = Whi + 8192,   *W_g1Wr_l = Wlo + 8192;
  const __bf16 *W_g2Wl_h = Whi + 16384,  *W_g2Wl_l = Wlo + 16384;
  const __bf16 *W_g2Wr_h = Whi + 32768,  *W_g2Wr_l = Wlo + 32768;
  const __bf16 *W_g3Wl_h = Whi + 49152,  *W_g3Wl_l = Wlo + 49152;
  const __bf16 *W_g3Wr_h = Whi + 65536,  *W_g3Wr_l = Wlo + 65536;
  const __bf16 *W_t2W_h  = Whi + 81920,  *W_t2W_l  = Wlo + 81920;
  const __bf16 *W_d1W_h  = Whi + 90112,  *W_d1W_l  = Wlo + 90112;
  const __bf16 *W_d2Wl_h = Whi + 98304,  *W_d2Wl_l = Wlo + 98304;
  const __bf16 *W_d2Wr_h = Whi + 114688, *W_d2Wr_l = Wlo + 114688;
  const __bf16 *W_d3Wl_h = Whi + 131072, *W_d3Wl_l = Wlo + 131072;
  const __bf16 *W_d3Wr_h = Whi + 139264, *W_d3Wr_l = Wlo + 139264;

  // --- prep: pre-split x and all weights ---
  split_x_kernel<<<(int)((N64 + 1023) / 1024), 256, 0, stream>>>(x, xhi, xlo, (int)N64);
  split_w_kernel<<<144, 256, 0, stream>>>(g1Wl, g1Wr, g2Wl, g2Wr, g3Wl, g3Wr,
                                          t2W, d1W, d2Wl, d2Wr, d3Wl, d3Wr, Whi, Wlo);

  // --- CSR build: one atomic round + hierarchical scan + atomic-free scatter ---
  hipMemsetAsync(cnt, 0, (size_t)N * sizeof(int), stream);
  count_rank_kernel<<<(E + 255) / 256, 256, 0, stream>>>(dst, cnt, rank, E);
  scan_blk_kernel<<<SB, 1024, 0, stream>>>(cnt, rowp, inv, bsum, N);
  scan_sums_kernel<<<1, 1024, 0, stream>>>(bsum, rowp, SB, N);
  scan_add_kernel<<<SB, 1024, 0, stream>>>(rowp, bsum, N);
  scatter_kernel<<<(E + 255) / 256, 256, 0, stream>>>(src, dst, rowp, rank, esrc, E);

  // ggn1: x(64) -> act1 s16, tanh  [A = exact x split; mean = pair]
  gather_f32s_kernel<<<GB, 256, 0, stream>>>(x, esrc, rowp, inv, Mhi, Mlo, N);
  node_mfma_kernel<64, 128, ACT_TANH, true, false, true, 2, false, 0, 0><<<NB, 512, 0, stream>>>(
      xhi, xlo, Mhi, Mlo, W_g1Wr_h, W_g1Wr_l, W_g1Wl_h, W_g1Wl_l, g1b, nullptr,
      nullptr, nullptr, act1, nullptr, nullptr, N);

  // ggn2: act1 -> act2 s16, tanh  [s16 gather -> s16 mean; s16 A]
  gather_s16_kernel<<<GB, 256, 0, stream>>>(act1, esrc, rowp, inv, Ms16, N);
  node_mfma_kernel<128, 128, ACT_TANH, true, false, true, 2, false, 2, 2><<<NB, 512, 0, stream>>>(
      (const __bf16*)act1, nullptr, (const __bf16*)Ms16, nullptr,
      W_g2Wr_h, W_g2Wr_l, W_g2Wl_h, W_g2Wl_l,
      g2b, nullptr, nullptr, nullptr, act2, nullptr, nullptr, N);

  // ggn3: act2 -> act1 s16, tanh  [s16 gather -> s16 mean; s16 A]
  gather_s16_kernel<<<GB, 256, 0, stream>>>(act2, esrc, rowp, inv, Ms16, N);
  node_mfma_kernel<128, 128, ACT_TANH, true, false, true, 2, false, 2, 2><<<NB, 512, 0, stream>>>(
      (const __bf16*)act2, nullptr, (const __bf16*)Ms16, nullptr,
      W_g3Wr_h, W_g3Wr_l, W_g3Wl_h, W_g3Wl_l,
      g3b, nullptr, nullptr, nullptr, act1, nullptr, nullptr, N);

  // tr2: act1(128, s16) -> mu(64) fp32 + lv fp32 + split(muhi/mulo)
  node_mfma_kernel<128, 64, ACT_NONE, false, false, true, 0, true, 2, 0><<<NB, 512, 0, stream>>>(
      (const __bf16*)act1, nullptr, nullptr, nullptr, W_t2W_h, W_t2W_l, nullptr, nullptr,
      t2b, nullptr, mu, lv, nullptr, muhi, mulo, N);

  // dec1: mu(64) -> shB fp16 ONLY, leaky
  node_mfma_kernel<64, 128, ACT_LEAKY, false, false, true, 1, false, 0, 0><<<NB, 512, 0, stream>>>(
      muhi, mulo, nullptr, nullptr, W_d1W_h, W_d1W_l, nullptr, nullptr, d1b, nullptr,
      nullptr, nullptr, shB, nullptr, nullptr, N);

  // dec2: A = shB fp16 (ASRC=1); mean = fp16 (MSRC=1); out -> shA fp16, leaky
  gather_h128_kernel<<<GB, 256, 0, stream>>>(shB, esrc, rowp, inv, Mh16, N);
  node_mfma_kernel<128, 128, ACT_LEAKY, true, false, true, 1, false, 1, 1><<<NB, 512, 0, stream>>>(
      (const __bf16*)shB, nullptr, (const __bf16*)Mh16, nullptr,
      W_d2Wr_h, W_d2Wr_l, W_d2Wl_h, W_d2Wl_l,
      d2b, nullptr, nullptr, nullptr, shA, nullptr, nullptr, N);

  // dec3 (linearity): shC = fp16(shA@Wl^T); gather -> meanF;
  // hBf = tanh(meanF + shA@Wr + b)
  node_mfma_kernel<128, 64, ACT_NONE, false, false, false, 1, false, 1, 0><<<NB, 512, 0, stream>>>(
      (const __bf16*)shA, nullptr, nullptr, nullptr, W_d3Wl_h, W_d3Wl_l, nullptr, nullptr,
      nullptr, nullptr, nullptr, nullptr, shC, nullptr, nullptr, N);
  gather_h64_kernel<<<GB, 256, 0, stream>>>(shC, esrc, rowp, inv, meanF, N);
  node_mfma_kernel<128, 64, ACT_TANH, false, true, true, 0, false, 1, 0><<<NB, 512, 0, stream>>>(
      (const __bf16*)shA, nullptr, nullptr, nullptr, W_d3Wr_h, W_d3Wr_l, nullptr, nullptr,
      d3b, meanF, hBf, nullptr, nullptr, nullptr, nullptr, N);

  // dec4 (linearity, fp32): y4 = hBf@Wl^T (3-pad-4); gather4; out = mean4 + b + hBf@Wr
  dec4_pre_kernel<<<GB, 256, 0, stream>>>(hBf, d4Wl, y4, N);
  gather_mean4_kernel<<<(N + 255) / 256, 256, 0, stream>>>(y4, esrc, rowp, inv, mean4, N);
  dec4_final_kernel<<<GB, 256, 0, stream>>>(hBf, mean4, d4Wr, d4b, out, N);
}

// Round 13
// 838.382 us; speedup vs baseline: 1.0697x; 1.0428x over previous
//
#include <hip/hip_runtime.h>
#include <cmath>

// ---------------------------------------------------------------------------
// GCN_Message: graph VAE forward. Round 22 (= exact R19 revert, best=845us):
//   - R21 (s16/fp16 mean encodings) REGRESSED +29us: phase-1 mean decode
//     added ~200 VALU/k-step to GEMMs whose critical path already carries
//     the A-decode; traffic saved (~13MB/GEMM) was worth less. Reverted.
//   - R20 fused-CSR and R18 sort-CSR both measured worse than R19's
//     count_rank(68us, atomic floor) + scan + scatter. Kept R19 CSR.
//   - Occupancy note: GEMM VGPR=116 caps 16 waves/CU == LDS cap; halving
//     LDS (Wlo direct) gains nothing. Register-bound plateau.
//   - Decoder fp16 A-path (R19). GEMM: 512-thd BM=256 (R17), W-persistent
//     LDS (R16). Encoder acts s16 (R14). 3-term split-bf16 MFMA (R6).
// ---------------------------------------------------------------------------

constexpr int ACT_NONE = 0, ACT_TANH = 1, ACT_LEAKY = 2;
constexpr int SCAN_CHUNK = 4096;  // 1024 threads x 4 items

typedef __attribute__((ext_vector_type(8))) __bf16 bf16x8;
typedef __attribute__((ext_vector_type(4))) float f32x4;
typedef __attribute__((ext_vector_type(4))) unsigned short u16x4;
typedef __attribute__((ext_vector_type(8))) unsigned short u16x8;

__device__ __forceinline__ unsigned short f2h(float x) {
  _Float16 h = (_Float16)x;
  unsigned short u;
  __builtin_memcpy(&u, &h, 2);
  return u;
}
__device__ __forceinline__ float h2f(unsigned short s) {
  _Float16 h;
  __builtin_memcpy(&h, &s, 2);
  return (float)h;
}
__device__ __forceinline__ float hlo(unsigned int u) {
  return h2f((unsigned short)(u & 0xffffu));
}
__device__ __forceinline__ float hhi(unsigned int u) {
  return h2f((unsigned short)(u >> 16));
}
__device__ __forceinline__ void split_bf16(float x, __bf16& h, __bf16& l) {
  h = (__bf16)x;
  l = (__bf16)(x - (float)h);
}
__device__ __forceinline__ unsigned short b2u(__bf16 b) {
  unsigned short u;
  __builtin_memcpy(&u, &b, 2);
  return u;
}

// elementwise split: fp32 -> bf16 hi/lo (total % 4 == 0)
__global__ __launch_bounds__(256) void split_x_kernel(const float* __restrict__ in,
                                                      __bf16* __restrict__ hi,
                                                      __bf16* __restrict__ lo, int total) {
  int i = (blockIdx.x * 256 + threadIdx.x) * 4;
  if (i >= total) return;
  float4 v = *(const float4*)(in + i);
  float vv[4] = {v.x, v.y, v.z, v.w};
  u16x4 h, l;
#pragma unroll
  for (int j = 0; j < 4; ++j) {
    __bf16 hb, lb;
    split_bf16(vv[j], hb, lb);
    h[j] = b2u(hb);
    l[j] = b2u(lb);
  }
  *(u16x4*)(hi + i) = h;
  *(u16x4*)(lo + i) = l;
}

// one-shot split of all 12 GEMM weight matrices into Whi/Wlo at fixed offsets
__global__ __launch_bounds__(256) void split_w_kernel(
    const float* p0, const float* p1, const float* p2, const float* p3,
    const float* p4, const float* p5, const float* p6, const float* p7,
    const float* p8, const float* p9, const float* p10, const float* p11,
    __bf16* __restrict__ hi, __bf16* __restrict__ lo) {
  int b = blockIdx.x;
  const float* src;
  int boff, doff;
  if      (b < 8)   { src = p0;  boff = b;       doff = 0; }
  else if (b < 16)  { src = p1;  boff = b - 8;   doff = 8192; }
  else if (b < 32)  { src = p2;  boff = b - 16;  doff = 16384; }
  else if (b < 48)  { src = p3;  boff = b - 32;  doff = 32768; }
  else if (b < 64)  { src = p4;  boff = b - 48;  doff = 49152; }
  else if (b < 80)  { src = p5;  boff = b - 64;  doff = 65536; }
  else if (b < 88)  { src = p6;  boff = b - 80;  doff = 81920; }
  else if (b < 96)  { src = p7;  boff = b - 88;  doff = 90112; }
  else if (b < 112) { src = p8;  boff = b - 96;  doff = 98304; }
  else if (b < 128) { src = p9;  boff = b - 112; doff = 114688; }
  else if (b < 136) { src = p10; boff = b - 128; doff = 131072; }
  else              { src = p11; boff = b - 136; doff = 139264; }
  int i = boff * 1024 + threadIdx.x * 4;
  float4 v = *(const float4*)(src + i);
  float vv[4] = {v.x, v.y, v.z, v.w};
  u16x4 h, l;
#pragma unroll
  for (int j = 0; j < 4; ++j) {
    __bf16 hb, lb;
    split_bf16(vv[j], hb, lb);
    h[j] = b2u(hb);
    l[j] = b2u(lb);
  }
  *(u16x4*)(hi + doff + i) = h;
  *(u16x4*)(lo + doff + i) = l;
}

// pass 1: rank[e] = within-segment index; cnt accumulates degrees
__global__ __launch_bounds__(256) void count_rank_kernel(const int* __restrict__ dst,
                                                         int* __restrict__ cnt,
                                                         int* __restrict__ rank, int E) {
  int e = blockIdx.x * 256 + threadIdx.x;
  if (e < E) rank[e] = atomicAdd(&cnt[dst[e]], 1);
}

// scan phase A: per-block (4096-elem) exclusive scan -> rowptr (local),
// block total -> bsum; also inv = 1/max(cnt,1)
__global__ __launch_bounds__(1024) void scan_blk_kernel(const int* __restrict__ cnt,
                                                        int* __restrict__ rowptr,
                                                        float* __restrict__ inv,
                                                        int* __restrict__ bsum, int n) {
  __shared__ int wsum[17];
  const int lane = threadIdx.x & 63;
  const int wid = threadIdx.x >> 6;
  const int i0 = blockIdx.x * SCAN_CHUNK + threadIdx.x * 4;
  int v[4];
  if (i0 + 3 < n) {
    int4 t = *(const int4*)(cnt + i0);
    v[0] = t.x; v[1] = t.y; v[2] = t.z; v[3] = t.w;
  } else {
#pragma unroll
    for (int j = 0; j < 4; ++j) v[j] = (i0 + j < n) ? cnt[i0 + j] : 0;
  }
#pragma unroll
  for (int j = 0; j < 4; ++j)
    if (i0 + j < n) inv[i0 + j] = 1.0f / (float)(v[j] > 1 ? v[j] : 1);
  const int s = v[0] + v[1] + v[2] + v[3];
  int x = s;
#pragma unroll
  for (int off = 1; off < 64; off <<= 1) {
    int t = __shfl_up(x, off);
    if (lane >= off) x += t;
  }
  if (lane == 63) wsum[wid + 1] = x;
  __syncthreads();
  if (threadIdx.x == 0) {
    wsum[0] = 0;
    for (int w = 1; w <= 16; ++w) wsum[w] += wsum[w - 1];
    bsum[blockIdx.x] = wsum[16];
  }
  __syncthreads();
  int p = wsum[wid] + x - s;
#pragma unroll
  for (int j = 0; j < 4; ++j) {
    if (i0 + j < n) rowptr[i0 + j] = p;
    p += v[j];
  }
}

// scan phase B: one block exclusive-scans bsum[nb] in place (nb <= 1024);
// grand total -> rowptr[n]
__global__ __launch_bounds__(1024) void scan_sums_kernel(int* __restrict__ bsum,
                                                         int* __restrict__ rowptr,
                                                         int nb, int n) {
  __shared__ int wsum[17];
  const int lane = threadIdx.x & 63;
  const int wid = threadIdx.x >> 6;
  const int v = (threadIdx.x < nb) ? bsum[threadIdx.x] : 0;
  int x = v;
#pragma unroll
  for (int off = 1; off < 64; off <<= 1) {
    int t = __shfl_up(x, off);
    if (lane >= off) x += t;
  }
  if (lane == 63) wsum[wid + 1] = x;
  __syncthreads();
  if (threadIdx.x == 0) {
    wsum[0] = 0;
    for (int w = 1; w <= 16; ++w) wsum[w] += wsum[w - 1];
    rowptr[n] = wsum[16];
  }
  __syncthreads();
  if (threadIdx.x < nb) bsum[threadIdx.x] = wsum[wid] + x - v;
}

// scan phase C: add block offset back into rowptr
__global__ __launch_bounds__(1024) void scan_add_kernel(int* __restrict__ rowptr,
                                                        const int* __restrict__ bsum,
                                                        int n) {
  const int off = bsum[blockIdx.x];
  const int i0 = blockIdx.x * SCAN_CHUNK + threadIdx.x * 4;
  if (i0 + 3 < n) {
    int4 t = *(const int4*)(rowptr + i0);
    t.x += off; t.y += off; t.z += off; t.w += off;
    *(int4*)(rowptr + i0) = t;
  } else {
    for (int j = 0; j < 4; ++j)
      if (i0 + j < n) rowptr[i0 + j] += off;
  }
}

// pass 2: atomic-free scatter
__global__ __launch_bounds__(256) void scatter_kernel(const int* __restrict__ src,
                                                      const int* __restrict__ dst,
                                                      const int* __restrict__ rowptr,
                                                      const int* __restrict__ rank,
                                                      int* __restrict__ esrc, int E) {
  int e = blockIdx.x * 256 + threadIdx.x;
  if (e < E) esrc[rowptr[dst[e]] + rank[e]] = src[e];
}

// fp32 gather (ggn1, D=64 from x): wave per node; writes split bf16 mean
__global__ __launch_bounds__(256) void gather_f32s_kernel(
    const float* __restrict__ in, const int* __restrict__ esrc,
    const int* __restrict__ rowptr, const float* __restrict__ inv,
    __bf16* __restrict__ Mhi, __bf16* __restrict__ Mlo, int n) {
  const int node = blockIdx.x * 4 + (threadIdx.x >> 6);
  const int lane = threadIdx.x & 63;
  if (node >= n) return;
  const int beg = rowptr[node];
  const int end = rowptr[node + 1];
  const float iv = inv[node];
  float a0 = 0.f, a1 = 0.f, a2 = 0.f, a3 = 0.f;
  for (int b = beg; b < end; b += 64) {
    int m = end - b;
    if (m > 64) m = 64;
    int myi = (lane < m) ? esrc[b + lane] : 0;
    int s = 0;
    for (; s + 4 <= m; s += 4) {
      int i0 = __shfl(myi, s);
      int i1 = __shfl(myi, s + 1);
      int i2 = __shfl(myi, s + 2);
      int i3 = __shfl(myi, s + 3);
      a0 += in[(size_t)i0 * 64 + lane];
      a1 += in[(size_t)i1 * 64 + lane];
      a2 += in[(size_t)i2 * 64 + lane];
      a3 += in[(size_t)i3 * 64 + lane];
    }
    for (; s < m; ++s) {
      int i0 = __shfl(myi, s);
      a0 += in[(size_t)i0 * 64 + lane];
    }
  }
  float mv = ((a0 + a1) + (a2 + a3)) * iv;
  __bf16 h, l;
  split_bf16(mv, h, l);
  Mhi[(size_t)node * 64 + lane] = h;
  Mlo[(size_t)node * 64 + lane] = l;
}

// int16 Q1.15 gather (encoder ggn2/ggn3): EXACT int32 neighbor sum;
// fp32 mean split to bf16 hi/lo pairs.
__global__ __launch_bounds__(256) void gather_s16_kernel(
    const unsigned short* __restrict__ inq, const int* __restrict__ esrc,
    const int* __restrict__ rowptr, const float* __restrict__ inv,
    __bf16* __restrict__ Mhi, __bf16* __restrict__ Mlo, int n) {
  const int node = blockIdx.x * 4 + (threadIdx.x >> 6);
  const int lane = threadIdx.x & 63;
  if (node >= n) return;
  const int beg = rowptr[node];
  const int end = rowptr[node + 1];
  const float iv = inv[node] * (1.0f / 32767.0f);
  const unsigned int* bu = (const unsigned int*)inq;
  int a0l = 0, a0h = 0, a1l = 0, a1h = 0;
  int a2l = 0, a2h = 0, a3l = 0, a3h = 0;
  for (int b = beg; b < end; b += 64) {
    int m = end - b;
    if (m > 64) m = 64;
    int myi = (lane < m) ? esrc[b + lane] : 0;
    int s = 0;
    for (; s + 4 <= m; s += 4) {
      int i0 = __shfl(myi, s);
      int i1 = __shfl(myi, s + 1);
      int i2 = __shfl(myi, s + 2);
      int i3 = __shfl(myi, s + 3);
      unsigned int u0 = bu[(size_t)i0 * 64 + lane];
      unsigned int u1 = bu[(size_t)i1 * 64 + lane];
      unsigned int u2 = bu[(size_t)i2 * 64 + lane];
      unsigned int u3 = bu[(size_t)i3 * 64 + lane];
      a0l += (int)(short)u0; a0h += ((int)u0) >> 16;
      a1l += (int)(short)u1; a1h += ((int)u1) >> 16;
      a2l += (int)(short)u2; a2h += ((int)u2) >> 16;
      a3l += (int)(short)u3; a3h += ((int)u3) >> 16;
    }
    for (; s < m; ++s) {
      int i0 = __shfl(myi, s);
      unsigned int u0 = bu[(size_t)i0 * 64 + lane];
      a0l += (int)(short)u0; a0h += ((int)u0) >> 16;
    }
  }
  float rx = (float)((a0l + a1l) + (a2l + a3l)) * iv;
  float ry = (float)((a0h + a1h) + (a2h + a3h)) * iv;
  __bf16 h0, l0, h1, l1;
  split_bf16(rx, h0, l0);
  split_bf16(ry, h1, l1);
  ((unsigned int*)Mhi)[(size_t)node * 64 + lane] =
      (unsigned int)b2u(h0) | ((unsigned int)b2u(h1) << 16);
  ((unsigned int*)Mlo)[(size_t)node * 64 + lane] =
      (unsigned int)b2u(l0) | ((unsigned int)b2u(l1) << 16);
}

// fp16 gather, D=128 (dec2): wave per node; writes split bf16 mean
__global__ __launch_bounds__(256) void gather_h128_kernel(
    const unsigned short* __restrict__ inh, const int* __restrict__ esrc,
    const int* __restrict__ rowptr, const float* __restrict__ inv,
    __bf16* __restrict__ Mhi, __bf16* __restrict__ Mlo, int n) {
  const int node = blockIdx.x * 4 + (threadIdx.x >> 6);
  const int lane = threadIdx.x & 63;
  if (node >= n) return;
  const int beg = rowptr[node];
  const int end = rowptr[node + 1];
  const float iv = inv[node];
  const unsigned int* bu = (const unsigned int*)inh;
  float a0x = 0.f, a0y = 0.f, a1x = 0.f, a1y = 0.f;
  float a2x = 0.f, a2y = 0.f, a3x = 0.f, a3y = 0.f;
  for (int b = beg; b < end; b += 64) {
    int m = end - b;
    if (m > 64) m = 64;
    int myi = (lane < m) ? esrc[b + lane] : 0;
    int s = 0;
    for (; s + 4 <= m; s += 4) {
      int i0 = __shfl(myi, s);
      int i1 = __shfl(myi, s + 1);
      int i2 = __shfl(myi, s + 2);
      int i3 = __shfl(myi, s + 3);
      unsigned int u0 = bu[(size_t)i0 * 64 + lane];
      unsigned int u1 = bu[(size_t)i1 * 64 + lane];
      unsigned int u2 = bu[(size_t)i2 * 64 + lane];
      unsigned int u3 = bu[(size_t)i3 * 64 + lane];
      a0x += hlo(u0); a0y += hhi(u0);
      a1x += hlo(u1); a1y += hhi(u1);
      a2x += hlo(u2); a2y += hhi(u2);
      a3x += hlo(u3); a3y += hhi(u3);
    }
    for (; s < m; ++s) {
      int i0 = __shfl(myi, s);
      unsigned int u0 = bu[(size_t)i0 * 64 + lane];
      a0x += hlo(u0); a0y += hhi(u0);
    }
  }
  float rx = ((a0x + a1x) + (a2x + a3x)) * iv;
  float ry = ((a0y + a1y) + (a2y + a3y)) * iv;
  __bf16 h0, l0, h1, l1;
  split_bf16(rx, h0, l0);
  split_bf16(ry, h1, l1);
  ((unsigned int*)Mhi)[(size_t)node * 64 + lane] =
      (unsigned int)b2u(h0) | ((unsigned int)b2u(h1) << 16);
  ((unsigned int*)Mlo)[(size_t)node * 64 + lane] =
      (unsigned int)b2u(l0) | ((unsigned int)b2u(l1) << 16);
}

// fp16 gather, D=64 (dec3): half-wave per neighbor-pair member; fp32 out
__global__ __launch_bounds__(256) void gather_h64_kernel(
    const unsigned short* __restrict__ inh, const int* __restrict__ esrc,
    const int* __restrict__ rowptr, const float* __restrict__ inv,
    float* __restrict__ meanb, int n) {
  const int node = blockIdx.x * 4 + (threadIdx.x >> 6);
  const int lane = threadIdx.x & 63;
  if (node >= n) return;
  const int beg = rowptr[node];
  const int end = rowptr[node + 1];
  const float iv = inv[node];
  const unsigned int* bu = (const unsigned int*)inh;
  const int half = lane >> 5;
  const int hl = lane & 31;
  float ax = 0.f, ay = 0.f, bx = 0.f, by = 0.f;
  for (int b = beg; b < end; b += 64) {
    int m = end - b;
    if (m > 64) m = 64;
    int myi = (lane < m) ? esrc[b + lane] : 0;
    int s = 0;
    for (; s + 4 <= m; s += 4) {
      int i0 = __shfl(myi, s + half);
      int i1 = __shfl(myi, s + 2 + half);
      unsigned int u0 = bu[(size_t)i0 * 32 + hl];
      unsigned int u1 = bu[(size_t)i1 * 32 + hl];
      ax += hlo(u0); ay += hhi(u0);
      bx += hlo(u1); by += hhi(u1);
    }
    for (; s < m; s += 2) {
      int t = s + half;
      if (t < m) {
        int i0 = __shfl(myi, t);
        unsigned int u0 = bu[(size_t)i0 * 32 + hl];
        ax += hlo(u0); ay += hhi(u0);
      }
    }
  }
  float sx = ax + bx, sy = ay + by;
  sx += __shfl_xor(sx, 32);
  sy += __shfl_xor(sy, 32);
  if (half == 0)
    ((float2*)meanb)[(size_t)node * 32 + hl] = make_float2(sx * iv, sy * iv);
}

// thread per node: mean over 4-wide (padded float4) rows
__global__ __launch_bounds__(256) void gather_mean4_kernel(
    const float* __restrict__ y4, const int* __restrict__ esrc,
    const int* __restrict__ rowptr, const float* __restrict__ inv,
    float* __restrict__ mean4, int n) {
  int i = blockIdx.x * 256 + threadIdx.x;
  if (i >= n) return;
  const int beg = rowptr[i], end = rowptr[i + 1];
  const float iv = inv[i];
  float sx = 0.f, sy = 0.f, sz = 0.f;
  const float4* b = (const float4*)y4;
  for (int j = beg; j < end; ++j) {
    float4 v = b[esrc[j]];
    sx += v.x; sy += v.y; sz += v.z;
  }
  ((float4*)mean4)[i] = make_float4(sx * iv, sy * iv, sz * iv, 0.f);
}

// out[row,col] = act( (AGG ? mean@Wl^T : 0) + (ADDMEAN ? meanF : 0)
//                     + in@Wr^T + (BIAS ? b : 0) )
// 512-thread blocks (8 waves), BM=256; W panel persists in LDS per phase
// (row stride DI+8); A streamed global->VGPR, k-loop fully unrolled.
// ASRC: 0 = A is bf16 hi/lo pair; 1 = A is fp16 single (convert+split in
// VGPRs); 2 = A is s16 Q1.15 (convert+split in VGPRs). Phase-1 (mean)
// operand is always the split pair Mhi/Mlo.
template <int DI, int DO, int ACT, bool AGG, bool ADDMEAN, bool BIAS, int SH,
          bool OSPLIT, int ASRC>
__global__ __launch_bounds__(512) void node_mfma_kernel(
    const __bf16* __restrict__ Ahi, const __bf16* __restrict__ Alo,
    const __bf16* __restrict__ Mhi, const __bf16* __restrict__ Mlo,
    const __bf16* __restrict__ Wrhi, const __bf16* __restrict__ Wrlo,
    const __bf16* __restrict__ Wlhi, const __bf16* __restrict__ Wllo,
    const float* __restrict__ bias, const float* __restrict__ meanF,
    float* __restrict__ out, float* __restrict__ out2,
    unsigned short* __restrict__ outh,
    __bf16* __restrict__ ohi, __bf16* __restrict__ olo, int n) {
  constexpr int BM = 256;
  constexpr int KSW = DI + 8;
  constexpr int CT = DO / 16;
  constexpr int EL = DO * DI / 512;
  __shared__ __align__(16) __bf16 Ws_hi[DO * KSW];
  __shared__ __align__(16) __bf16 Ws_lo[DO * KSW];

  const int wv = threadIdx.x >> 6;
  const int lane = threadIdx.x & 63;
  const int lm = lane & 15;
  const int lq = lane >> 4;
  const int row0 = blockIdx.x * BM;

  f32x4 acc[2][CT];
#pragma unroll
  for (int rt = 0; rt < 2; ++rt)
#pragma unroll
    for (int ct = 0; ct < CT; ++ct) acc[rt][ct] = (f32x4){0.f, 0.f, 0.f, 0.f};

  bf16x8 zf;
#pragma unroll
  for (int j = 0; j < 8; ++j) zf[j] = (__bf16)0.f;

  const int rA0 = row0 + wv * 32 + lm;
  const int rA1 = rA0 + 16;
  const bool ok0 = rA0 < n;
  const bool ok1 = rA1 < n;
  const int kofs = lq * 8;

  const int sc = (threadIdx.x * EL) / DI;
  const int sk = (threadIdx.x * EL) % DI;

  const int nphase = AGG ? 2 : 1;
  for (int phase = 0; phase < nphase; ++phase) {
    const __bf16* WH = (phase == 0) ? Wrhi : Wlhi;
    const __bf16* WL = (phase == 0) ? Wrlo : Wllo;
    if (phase > 0) __syncthreads();
#pragma unroll
    for (int j = 0; j < EL / 8; ++j) {
      *(bf16x8*)(&Ws_hi[sc * KSW + sk + j * 8]) =
          *(const bf16x8*)(WH + (size_t)sc * DI + sk + j * 8);
      *(bf16x8*)(&Ws_lo[sc * KSW + sk + j * 8]) =
          *(const bf16x8*)(WL + (size_t)sc * DI + sk + j * 8);
    }
    __syncthreads();

    const __bf16* AH = (phase == 0) ? Ahi : Mhi;
    const __bf16* AL = (phase == 0) ? Alo : Mlo;
#pragma unroll
    for (int k0 = 0; k0 < DI; k0 += 32) {
      bf16x8 ah[2], al[2];
      if ((ASRC == 1 || ASRC == 2) && phase == 0) {
        // u16-coded A (fp16 or s16 Q1.15): load 8 shorts/row, convert+split
        const unsigned short* Q = (const unsigned short*)AH;
        u16x8 q0, q1;
        if (ok0) q0 = *(const u16x8*)(Q + (size_t)rA0 * DI + k0 + kofs);
        else {
#pragma unroll
          for (int j = 0; j < 8; ++j) q0[j] = 0;
        }
        if (ok1) q1 = *(const u16x8*)(Q + (size_t)rA1 * DI + k0 + kofs);
        else {
#pragma unroll
          for (int j = 0; j < 8; ++j) q1[j] = 0;
        }
#pragma unroll
        for (int j = 0; j < 8; ++j) {
          float v0, v1;
          if (ASRC == 1) {
            v0 = h2f(q0[j]);
            v1 = h2f(q1[j]);
          } else {
            v0 = (float)(short)q0[j] * (1.0f / 32767.0f);
            v1 = (float)(short)q1[j] * (1.0f / 32767.0f);
          }
          __bf16 hb, lb;
          split_bf16(v0, hb, lb);
          ah[0][j] = hb; al[0][j] = lb;
          split_bf16(v1, hb, lb);
          ah[1][j] = hb; al[1][j] = lb;
        }
      } else {
        ah[0] = ok0 ? *(const bf16x8*)(AH + (size_t)rA0 * DI + k0 + kofs) : zf;
        al[0] = ok0 ? *(const bf16x8*)(AL + (size_t)rA0 * DI + k0 + kofs) : zf;
        ah[1] = ok1 ? *(const bf16x8*)(AH + (size_t)rA1 * DI + k0 + kofs) : zf;
        al[1] = ok1 ? *(const bf16x8*)(AL + (size_t)rA1 * DI + k0 + kofs) : zf;
      }
#pragma unroll
      for (int ct = 0; ct < CT; ++ct) {
        const int c = ct * 16 + lm;
        bf16x8 bh = *(const bf16x8*)(&Ws_hi[c * KSW + k0 + kofs]);
        bf16x8 bl = *(const bf16x8*)(&Ws_lo[c * KSW + k0 + kofs]);
#pragma unroll
        for (int rt = 0; rt < 2; ++rt) {
          acc[rt][ct] = __builtin_amdgcn_mfma_f32_16x16x32_bf16(ah[rt], bh, acc[rt][ct], 0, 0, 0);
          acc[rt][ct] = __builtin_amdgcn_mfma_f32_16x16x32_bf16(al[rt], bh, acc[rt][ct], 0, 0, 0);
          acc[rt][ct] = __builtin_amdgcn_mfma_f32_16x16x32_bf16(ah[rt], bl, acc[rt][ct], 0, 0, 0);
        }
      }
    }
  }

#pragma unroll
  for (int rt = 0; rt < 2; ++rt)
#pragma unroll
    for (int ct = 0; ct < CT; ++ct) {
      const int col = ct * 16 + lm;
      const float bval = BIAS ? bias[col] : 0.f;
      f32x4 a = acc[rt][ct];
#pragma unroll
      for (int r = 0; r < 4; ++r) {
        const int row = row0 + wv * 32 + rt * 16 + lq * 4 + r;
        if (row < n) {
          float t = a[r] + bval;
          if (ADDMEAN) t += meanF[(size_t)row * DO + col];
          if (ACT == ACT_TANH) t = tanhf(t);
          else if (ACT == ACT_LEAKY) t = (t > 0.f) ? t : 0.01f * t;
          if (out) out[(size_t)row * DO + col] = t;
          if (out2) out2[(size_t)row * DO + col] = t;
          if constexpr (SH == 1) {
            if (outh) outh[(size_t)row * DO + col] = f2h(t);
          } else if constexpr (SH == 2) {
            if (outh)
              outh[(size_t)row * DO + col] =
                  (unsigned short)(short)__builtin_rintf(t * 32767.0f);
          }
          if constexpr (OSPLIT) {
            __bf16 hb, lb;
            split_bf16(t, hb, lb);
            ohi[(size_t)row * DO + col] = hb;
            olo[(size_t)row * DO + col] = lb;
          }
        }
      }
    }
}

// y4[node] = hB[node] @ Wl^T (3 outputs, padded float4); wave per node
__global__ __launch_bounds__(256) void dec4_pre_kernel(
    const float* __restrict__ hB, const float* __restrict__ Wl,
    float* __restrict__ y4, int n) {
  const int node = blockIdx.x * 4 + (threadIdx.x >> 6);
  const int lane = threadIdx.x & 63;
  if (node >= n) return;
  float v = hB[(size_t)node * 64 + lane];
  float p0 = v * Wl[lane];
  float p1 = v * Wl[64 + lane];
  float p2 = v * Wl[128 + lane];
#pragma unroll
  for (int off = 32; off >= 1; off >>= 1) {
    p0 += __shfl_xor(p0, off);
    p1 += __shfl_xor(p1, off);
    p2 += __shfl_xor(p2, off);
  }
  if (lane == 0) ((float4*)y4)[node] = make_float4(p0, p1, p2, 0.f);
}

// out = mean4 + b + hB@Wr^T, scattered layout (z2[:,:2], z2[:,2]); wave/node
__global__ __launch_bounds__(256) void dec4_final_kernel(
    const float* __restrict__ hB, const float* __restrict__ mean4,
    const float* __restrict__ Wr, const float* __restrict__ bias,
    float* __restrict__ out, int n) {
  const int node = blockIdx.x * 4 + (threadIdx.x >> 6);
  const int lane = threadIdx.x & 63;
  if (node >= n) return;
  float v = hB[(size_t)node * 64 + lane];
  float p0 = v * Wr[lane];
  float p1 = v * Wr[64 + lane];
  float p2 = v * Wr[128 + lane];
#pragma unroll
  for (int off = 32; off >= 1; off >>= 1) {
    p0 += __shfl_xor(p0, off);
    p1 += __shfl_xor(p1, off);
    p2 += __shfl_xor(p2, off);
  }
  if (lane == 0) {
    float4 m = ((const float4*)mean4)[node];
    out[2 * (size_t)node]     = p0 + m.x + bias[0];
    out[2 * (size_t)node + 1] = p1 + m.y + bias[1];
    out[2 * (size_t)n + node] = p2 + m.z + bias[2];
  }
}

extern "C" void kernel_launch(void* const* d_in, const int* in_sizes, int n_in,
                              void* d_out, int out_size, void* d_ws, size_t ws_size,
                              hipStream_t stream) {
  const float* x = (const float*)d_in[0];
  const int* ei = (const int*)d_in[1];
  const int N = in_sizes[0] / 64;
  const int E = in_sizes[1] / 2;
  const int* src = ei;
  const int* dst = ei + E;
  const float* g1Wl = (const float*)d_in[2];
  const float* g1b  = (const float*)d_in[3];
  const float* g1Wr = (const float*)d_in[4];
  const float* g2Wl = (const float*)d_in[5];
  const float* g2b  = (const float*)d_in[6];
  const float* g2Wr = (const float*)d_in[7];
  const float* g3Wl = (const float*)d_in[8];
  const float* g3b  = (const float*)d_in[9];
  const float* g3Wr = (const float*)d_in[10];
  const float* t2W  = (const float*)d_in[11];
  const float* t2b  = (const float*)d_in[12];
  const float* d1W  = (const float*)d_in[13];
  const float* d1b  = (const float*)d_in[14];
  const float* d2Wl = (const float*)d_in[15];
  const float* d2b  = (const float*)d_in[16];
  const float* d2Wr = (const float*)d_in[17];
  const float* d3Wl = (const float*)d_in[18];
  const float* d3b  = (const float*)d_in[19];
  const float* d3Wr = (const float*)d_in[20];
  const float* d4Wl = (const float*)d_in[21];
  const float* d4b  = (const float*)d_in[22];
  const float* d4Wr = (const float*)d_in[23];

  const size_t N64 = (size_t)N * 64;
  const size_t N128 = (size_t)N * 128;

  char* w = (char*)d_ws;
  auto alloc = [&](size_t bytes) {
    char* p = w;
    w += (bytes + 255) & ~(size_t)255;
    return p;
  };
  __bf16* Ahi = (__bf16*)alloc(N128 * 2);   // enc act1 s16; dec2-out shA fp16
  __bf16* Alo = (__bf16*)alloc(N128 * 2);   // enc act2 s16
  float*  meanF = (float*)alloc(N128 * 4);  // aliased below
  __bf16* xhi = (__bf16*)alloc(N64 * 2);    // also muhi, also shC
  __bf16* xlo = (__bf16*)alloc(N64 * 2);    // also mulo
  __bf16* Whi = (__bf16*)alloc(147456 * 2);
  __bf16* Wlo = (__bf16*)alloc(147456 * 2);
  int*    cnt = (int*)alloc((size_t)N * 4);
  float*  inv = (float*)alloc((size_t)N * 4);
  int*    rowp = (int*)alloc(((size_t)N + 1) * 4);
  int*    rank = (int*)alloc((size_t)E * 4);
  int*    esrc = (int*)alloc((size_t)E * 4);
  unsigned short* shB = (unsigned short*)alloc(N128 * 2);  // dec1 out fp16

  // encoder s16 activation buffers (alias Ahi/Alo; dead before decoder use)
  unsigned short* act1 = (unsigned short*)Ahi;  // ggn1 out; ggn2 in; ggn3 out; tr2 A
  unsigned short* act2 = (unsigned short*)Alo;  // ggn2 out; ggn3 in
  unsigned short* shA = (unsigned short*)Ahi;   // dec2 out fp16 (act1 dead after tr2)

  // aliases of meanF (disjoint lifetimes):
  __bf16* Mhi = (__bf16*)meanF;        // N x 128 bf16 (gather->GEMM phase 1)
  __bf16* Mlo = Mhi + N128;
  int*    bsum = (int*)meanF;          // scan block sums (CSR build only)
  float*  y4 = meanF;                  // N x 4 (dec4)
  float*  mean4 = meanF + 4 * (size_t)N;
  float*  hBf = meanF + N64;           // N x 64 f32 (dec3 out -> dec4)
  // aliases of xhi/xlo:
  __bf16* muhi = xhi;
  __bf16* mulo = xlo;
  unsigned short* shC = (unsigned short*)xhi;

  float* out = (float*)d_out;
  float* mu  = out + 3 * (size_t)N;  // N x 64
  float* lv  = mu + 64 * (size_t)N;  // N x 64 (logvar == mu)

  const int NB = (N + 255) / 256;  // 512-thread GEMM blocks, BM=256
  const int GB = (N + 3) / 4;
  const int SB = (N + SCAN_CHUNK - 1) / SCAN_CHUNK;

  // weight split offsets (bf16 elems) in Whi/Wlo
  const __bf16 *W_g1Wl_h = Whi + 0,      *W_g1Wl_l = Wlo + 0;
  const __bf16 *W_g1Wr_h = Whi + 8192,   *W_g1Wr_l = Wlo + 8192;
  const __bf16 *W_g2Wl_h = Whi + 16384,  *W_g2Wl_l = Wlo + 16384;
  const __bf16 *W_g2Wr_h = Whi + 32768,  *W_g2Wr_l = Wlo + 32768;
  const __bf16 *W_g3Wl_h = Whi + 49152,  *W_g3Wl_l = Wlo + 49152;
  const __bf16 *W_g3Wr_h = Whi + 65536,  *W_g3Wr_l = Wlo + 65536;
  const __bf16 *W_t2W_h  = Whi + 81920,  *W_t2W_l  = Wlo + 81920;
  const __bf16 *W_d1W_h  = Whi + 90112,  *W_d1W_l  = Wlo + 90112;
  const __bf16 *W_d2Wl_h = Whi + 98304,  *W_d2Wl_l = Wlo + 98304;
  const __bf16 *W_d2Wr_h = Whi + 114688, *W_d2Wr_l = Wlo + 114688;
  const __bf16 *W_d3Wl_h = Whi + 131072, *W_d3Wl_l = Wlo + 131072;
  const __bf16 *W_d3Wr_h = Whi + 139264, *W_d3Wr_l = Wlo + 139264;

  // --- prep: pre-split x and all weights ---
  split_x_kernel<<<(int)((N64 + 1023) / 1024), 256, 0, stream>>>(x, xhi, xlo, (int)N64);
  split_w_kernel<<<144, 256, 0, stream>>>(g1Wl, g1Wr, g2Wl, g2Wr, g3Wl, g3Wr,
                                          t2W, d1W, d2Wl, d2Wr, d3Wl, d3Wr, Whi, Wlo);

  // --- CSR build: one atomic round + hierarchical scan + atomic-free scatter ---
  hipMemsetAsync(cnt, 0, (size_t)N * sizeof(int), stream);
  count_rank_kernel<<<(E + 255) / 256, 256, 0, stream>>>(dst, cnt, rank, E);
  scan_blk_kernel<<<SB, 1024, 0, stream>>>(cnt, rowp, inv, bsum, N);
  scan_sums_kernel<<<1, 1024, 0, stream>>>(bsum, rowp, SB, N);
  scan_add_kernel<<<SB, 1024, 0, stream>>>(rowp, bsum, N);
  scatter_kernel<<<(E + 255) / 256, 256, 0, stream>>>(src, dst, rowp, rank, esrc, E);

  // ggn1: x(64) -> act1 s16, tanh  [A = exact x split]
  gather_f32s_kernel<<<GB, 256, 0, stream>>>(x, esrc, rowp, inv, Mhi, Mlo, N);
  node_mfma_kernel<64, 128, ACT_TANH, true, false, true, 2, false, 0><<<NB, 512, 0, stream>>>(
      xhi, xlo, Mhi, Mlo, W_g1Wr_h, W_g1Wr_l, W_g1Wl_h, W_g1Wl_l, g1b, nullptr,
      nullptr, nullptr, act1, nullptr, nullptr, N);

  // ggn2: act1 -> act2 s16, tanh  [s16 gather + s16 A]
  gather_s16_kernel<<<GB, 256, 0, stream>>>(act1, esrc, rowp, inv, Mhi, Mlo, N);
  node_mfma_kernel<128, 128, ACT_TANH, true, false, true, 2, false, 2><<<NB, 512, 0, stream>>>(
      (const __bf16*)act1, nullptr, Mhi, Mlo, W_g2Wr_h, W_g2Wr_l, W_g2Wl_h, W_g2Wl_l,
      g2b, nullptr, nullptr, nullptr, act2, nullptr, nullptr, N);

  // ggn3: act2 -> act1 s16, tanh  [s16 gather + s16 A]
  gather_s16_kernel<<<GB, 256, 0, stream>>>(act2, esrc, rowp, inv, Mhi, Mlo, N);
  node_mfma_kernel<128, 128, ACT_TANH, true, false, true, 2, false, 2><<<NB, 512, 0, stream>>>(
      (const __bf16*)act2, nullptr, Mhi, Mlo, W_g3Wr_h, W_g3Wr_l, W_g3Wl_h, W_g3Wl_l,
      g3b, nullptr, nullptr, nullptr, act1, nullptr, nullptr, N);

  // tr2: act1(128, s16) -> mu(64) fp32 + lv fp32 + split(muhi/mulo)
  node_mfma_kernel<128, 64, ACT_NONE, false, false, true, 0, true, 2><<<NB, 512, 0, stream>>>(
      (const __bf16*)act1, nullptr, nullptr, nullptr, W_t2W_h, W_t2W_l, nullptr, nullptr,
      t2b, nullptr, mu, lv, nullptr, muhi, mulo, N);

  // dec1: mu(64) -> shB fp16 ONLY, leaky
  node_mfma_kernel<64, 128, ACT_LEAKY, false, false, true, 1, false, 0><<<NB, 512, 0, stream>>>(
      muhi, mulo, nullptr, nullptr, W_d1W_h, W_d1W_l, nullptr, nullptr, d1b, nullptr,
      nullptr, nullptr, shB, nullptr, nullptr, N);

  // dec2: A = shB fp16 (ASRC=1); out -> shA fp16 ONLY, leaky  [fp16 gather]
  gather_h128_kernel<<<GB, 256, 0, stream>>>(shB, esrc, rowp, inv, Mhi, Mlo, N);
  node_mfma_kernel<128, 128, ACT_LEAKY, true, false, true, 1, false, 1><<<NB, 512, 0, stream>>>(
      (const __bf16*)shB, nullptr, Mhi, Mlo, W_d2Wr_h, W_d2Wr_l, W_d2Wl_h, W_d2Wl_l,
      d2b, nullptr, nullptr, nullptr, shA, nullptr, nullptr, N);

  // dec3 (linearity): shC = fp16(shA@Wl^T); gather -> meanF;
  // hBf = tanh(meanF + shA@Wr + b)  [A = shA fp16 via ASRC=1]
  node_mfma_kernel<128, 64, ACT_NONE, false, false, false, 1, false, 1><<<NB, 512, 0, stream>>>(
      (const __bf16*)shA, nullptr, nullptr, nullptr, W_d3Wl_h, W_d3Wl_l, nullptr, nullptr,
      nullptr, nullptr, nullptr, nullptr, shC, nullptr, nullptr, N);
  gather_h64_kernel<<<GB, 256, 0, stream>>>(shC, esrc, rowp, inv, meanF, N);
  node_mfma_kernel<128, 64, ACT_TANH, false, true, true, 0, false, 1><<<NB, 512, 0, stream>>>(
      (const __bf16*)shA, nullptr, nullptr, nullptr, W_d3Wr_h, W_d3Wr_l, nullptr, nullptr,
      d3b, meanF, hBf, nullptr, nullptr, nullptr, nullptr, N);

  // dec4 (linearity, fp32): y4 = hBf@Wl^T (3-pad-4); gather4; out = mean4 + b + hBf@Wr
  dec4_pre_kernel<<<GB, 256, 0, stream>>>(hBf, d4Wl, y4, N);
  gather_mean4_kernel<<<(N + 255) / 256, 256, 0, stream>>>(y4, esrc, rowp, inv, mean4, N);
  dec4_final_kernel<<<GB, 256, 0, stream>>>(hBf, mean4, d4Wr, d4b, out, N);
}